// Round 13
// baseline (562.223 us; speedup 1.0000x reference)
//
#include <hip/hip_runtime.h>
#include <cstdint>

typedef unsigned short u16;
typedef __attribute__((ext_vector_type(8))) short sh8;   // 8 bf16 (4 VGPRs)
typedef __attribute__((ext_vector_type(4))) float f32x4;

struct __align__(8) us4 { u16 x, y, z, w; };

__device__ __forceinline__ u16 f2bf(float f) {
  unsigned u = __float_as_uint(f);
  u += 0x7FFFu + ((u >> 16) & 1u);   // RNE
  return (u16)(u >> 16);
}
__device__ __forceinline__ float bf2f(u16 h) {
  return __uint_as_float((unsigned)h << 16);
}
// inverse norm: 1/max(sqrt(x),1e-12) == min(rsqrt(x),1e12)
__device__ __forceinline__ float invnorm(float nrm) {
  return fminf(rsqrtf(nrm), 1e12f);
}

// ---------------- block reductions (blockDim.x == 256) ----------------
__device__ __forceinline__ float blk_sum(float v, float* red) {
#pragma unroll
  for (int o = 32; o; o >>= 1) v += __shfl_xor(v, o);
  __syncthreads();
  if ((threadIdx.x & 63) == 0) red[threadIdx.x >> 6] = v;
  __syncthreads();
  return red[0] + red[1] + red[2] + red[3];
}
__device__ __forceinline__ float blk_max(float v, float* red) {
#pragma unroll
  for (int o = 32; o; o >>= 1) v = fmaxf(v, __shfl_xor(v, o));
  __syncthreads();
  if ((threadIdx.x & 63) == 0) red[threadIdx.x >> 6] = v;
  __syncthreads();
  return fmaxf(fmaxf(red[0], red[1]), fmaxf(red[2], red[3]));
}

__global__ void fillv(float* __restrict__ o, long n, float v) {
  long i = (long)blockIdx.x * blockDim.x + threadIdx.x;
  if (i < n) o[i] = v;
}

// ------- merged fp32 -> bf16, EXACT 1-D grid via block-offset prefix table -------
struct CvtN12 {
  const float* s[12];
  u16* d[12];
  long n4[12];
  int bofs[13];   // block-offset prefix; grid.x == bofs[12]
};
__global__ void cvt_many(CvtN12 c) {
  int blk = blockIdx.x;
  int z = 0;
  while (z < 11 && blk >= c.bofs[z + 1]) ++z;   // block-uniform scalar scan
  long i = (long)(blk - c.bofs[z]) * blockDim.x + threadIdx.x;
  if (i >= c.n4[z]) return;
  float4 v = ((const float4*)c.s[z])[i];
  us4 o; o.x = f2bf(v.x); o.y = f2bf(v.y); o.z = f2bf(v.z); o.w = f2bf(v.w);
  ((us4*)c.d[z])[i] = o;
}

#define GL16(gp, lp)                                                        \
  __builtin_amdgcn_global_load_lds(                                         \
      (const __attribute__((address_space(1))) void*)(gp),                  \
      (__attribute__((address_space(3))) void*)(lp), 16, 0, 0)

// ---- gemm256 body (256x256 tile, 8 waves, 2-slot 64KiB ring -> 2 blocks/CU,
//      counted vmcnt depth-2, XOR bank-swizzle, T5 setprio) ----
#define G256_PROLOG()                                                          \
  extern __shared__ u16 lds[];   /* 2 slots x (A 8192 + B 8192) u16 = 64 KiB */\
  int tid = threadIdx.x;                                                       \
  int wid = tid >> 6, lane = tid & 63;                                         \
  int wm = wid >> 2, wn = wid & 3;                                             \
  int bm = blockIdx.x, bn = blockIdx.y;                                        \
  int k0s = 0, nt;                                                             \
  if (kchunk) {                                                                \
    k0s = blockIdx.z * kchunk;                                                 \
    nt = kchunk >> 5;                                                          \
  } else {                                                                     \
    nt = K >> 5;                                                               \
  }                                                                            \
  const size_t baseArow = (size_t)bm * 256;                                    \
  const size_t baseBrow = (size_t)bn * 256;                                    \
  int ci = (wid << 6) + lane;                                                  \
  int rowS = ci >> 2;                                                          \
  int kcS = (ci ^ (ci >> 3)) & 3;                                              \
  const u16* gA0 = A + (baseArow + rowS) * lda + k0s + kcS * 8;                \
  const u16* gA1 = gA0 + (size_t)128 * lda;                                    \
  const u16* gB0 = B + (baseBrow + rowS) * ldb + k0s + kcS * 8;                \
  const u16* gB1 = gB0 + (size_t)128 * ldb;                                    \
  u16* dBase = lds + (wid << 9);                                               \
  int l15 = lane & 15, l4 = lane >> 4;                                         \
  int aoff[8], boff[4];                                                        \
  _Pragma("unroll") for (int fr = 0; fr < 8; ++fr) {                           \
    int by = (wm * 128 + fr * 16 + l15) * 64 + l4 * 16;                        \
    aoff[fr] = (by ^ (((by >> 7) & 3) << 4)) >> 1;                             \
  }                                                                            \
  _Pragma("unroll") for (int fc = 0; fc < 4; ++fc) {                           \
    int by = (wn * 64 + fc * 16 + l15) * 64 + l4 * 16;                         \
    boff[fc] = 8192 + ((by ^ (((by >> 7) & 3) << 4)) >> 1);                    \
  }                                                                            \
  f32x4 acc[8][4];                                                             \
  const f32x4 zf = {0.f, 0.f, 0.f, 0.f};                                       \
  _Pragma("unroll") for (int i = 0; i < 8; ++i)                                \
    _Pragma("unroll") for (int j = 0; j < 4; ++j) acc[i][j] = zf;

#define STAGE256(ts)                                                  \
  do {                                                                \
    int ss_ = (ts) & 1;                                               \
    int kk_ = (ts) << 5;                                              \
    u16* d_ = dBase + ss_ * 16384;                                    \
    GL16(gA0 + kk_, d_);                                              \
    GL16(gA1 + kk_, d_ + 4096);                                       \
    GL16(gB0 + kk_, d_ + 8192);                                       \
    GL16(gB1 + kk_, d_ + 12288);                                      \
  } while (0)

// 2-slot ring: prologue stages t0,t1; per tile {reads+MFMA -> barrier ->
// STAGE(t+2 into just-read slot) -> counted vmcnt -> barrier}.
#define G256_KLOOP()                                                           \
  STAGE256(0);                                                                 \
  STAGE256(1);                                                                 \
  asm volatile("s_waitcnt vmcnt(4)" ::: "memory");                             \
  __builtin_amdgcn_s_barrier();                                                \
  __builtin_amdgcn_sched_barrier(0);                                           \
  for (int t = 0; t < nt; ++t) {                                               \
    const u16* sl = lds + (t & 1) * 16384;                                     \
    sh8 af[8], bfv[4];                                                         \
    _Pragma("unroll") for (int fc = 0; fc < 4; ++fc)                           \
        bfv[fc] = *(const sh8*)(sl + boff[fc]);                                \
    _Pragma("unroll") for (int fr = 0; fr < 8; ++fr)                           \
        af[fr] = *(const sh8*)(sl + aoff[fr]);                                 \
    __builtin_amdgcn_s_setprio(1);                                             \
    _Pragma("unroll") for (int fr = 0; fr < 8; ++fr)                           \
      _Pragma("unroll") for (int fc = 0; fc < 4; ++fc)                         \
        acc[fr][fc] = __builtin_amdgcn_mfma_f32_16x16x32_bf16(                 \
            af[fr], bfv[fc], acc[fr][fc], 0, 0, 0);                            \
    __builtin_amdgcn_s_setprio(0);                                             \
    if (t + 1 < nt) {                                                          \
      __builtin_amdgcn_s_barrier();        /* slot (t&1) fully read */         \
      __builtin_amdgcn_sched_barrier(0);                                       \
      if (t + 2 < nt) {                                                        \
        STAGE256(t + 2);                   /* overwrite slot (t&1) */          \
        asm volatile("s_waitcnt vmcnt(4)" ::: "memory");  /* t+1 landed */     \
      } else {                                                                 \
        asm volatile("s_waitcnt vmcnt(0)" ::: "memory");                       \
      }                                                                        \
      __builtin_amdgcn_s_barrier();                                            \
      __builtin_amdgcn_sched_barrier(0);                                       \
    }                                                                          \
  }

// ================= plain 256x256 pipelined GEMM: C = A @ B^T =================
// kchunk > 0: split-K over blockIdx.z (C += z*M*N).
template <typename CT>
__global__ __launch_bounds__(512, 1) void gemm256(
    const u16* __restrict__ A, const u16* __restrict__ B, CT* __restrict__ C,
    int M, int N, int K, int lda, int ldb, int kchunk) {
  if (kchunk) C += (size_t)blockIdx.z * M * (size_t)N;
  G256_PROLOG();
  G256_KLOOP();
  // C/D layout (m89): col = lane&15, row = (lane>>4)*4 + reg
  int cr = l4 << 2, cc = l15;
  const size_t rbase = baseArow + wm * 128 + cr;
  const size_t cbase = baseBrow + wn * 64 + cc;
#pragma unroll
  for (int fr = 0; fr < 8; ++fr)
#pragma unroll
    for (int fc = 0; fc < 4; ++fc) {
      size_t cb = (rbase + fr * 16) * (size_t)N + cbase + fc * 16;
#pragma unroll
      for (int r = 0; r < 4; ++r) {
        float v = acc[fr][fc][r];
        if constexpr (sizeof(CT) == 2) C[cb + (size_t)r * N] = (CT)f2bf(v);
        else                           C[cb + (size_t)r * N] = v;
      }
    }
}

// ---------------- bf16 GEMM: C[M,N] = A[M,K] @ B[N,K]^T (128^2, m97) ----------------
// mode 0: plain | 1: split-K z | 2: batched z | 3: batched + causal tri |
// mode 4: batched + causal K-cap | 5: multi-M batched (Mz packed in zsB)
template <typename CT>
__global__ __launch_bounds__(256, 2) void gemm_bt(
    const u16* __restrict__ A, const u16* __restrict__ B, CT* __restrict__ C,
    int M, int N, int K, int lda, int ldb,
    int mode, long zsA, long zsB, long zsC) {
  int bm, bn;
  int z = blockIdx.z;
  if (mode == 3) {
    int t = blockIdx.x;
    int m = (int)floorf((sqrtf(8.f * t + 1.f) - 1.f) * 0.5f);
    while ((m + 1) * (m + 2) / 2 <= t) ++m;
    while (m * (m + 1) / 2 > t) --m;
    bm = m; bn = t - m * (m + 1) / 2;
  } else {
    bm = blockIdx.x; bn = blockIdx.y;
  }
  int k0s = 0, k0e = K;
  if (mode == 1) {
    int kc = K / gridDim.z;
    k0s = z * kc; k0e = k0s + kc;
    C += (size_t)z * M * (size_t)N;
  } else if (mode == 2 || mode == 3) {
    A += (size_t)z * zsA; B += (size_t)z * zsB; C += (size_t)z * zsC;
  } else if (mode == 4) {
    A += (size_t)z * zsA; B += (size_t)z * zsB; C += (size_t)z * zsC;
    k0e = (bm + 1) * 128;
  } else if (mode == 5) {
    int Mz = (int)((zsB >> (z * 16)) & 0xFFFF);
    if (bm * 128 >= Mz) return;
    A += (size_t)z * zsA; B += (size_t)z * 1048576; C += (size_t)z * zsC;
  }

  __shared__ __align__(16) u16 As[128 * 32];
  __shared__ __align__(16) u16 Bs[128 * 32];
  int tid = threadIdx.x, wid = tid >> 6, lane = tid & 63;
  int wr = (wid >> 1) << 6, wc = (wid & 1) << 6;
  int lr = lane & 15, lk = (lane >> 4) << 3;

  f32x4 acc[4][4];
  const f32x4 zf = {0.f, 0.f, 0.f, 0.f};
#pragma unroll
  for (int i = 0; i < 4; ++i)
#pragma unroll
    for (int j = 0; j < 4; ++j) acc[i][j] = zf;

  int r0 = tid >> 2, c0 = (tid & 3) << 3;
  const size_t baseA = (size_t)bm * 128, baseB = (size_t)bn * 128;
  const u16* Ab = A + baseA * lda;
  const u16* Bp = B + baseB * ldb;

  for (int k0 = k0s; k0 < k0e; k0 += 32) {
    GL16(Ab + (size_t)r0 * lda + k0 + c0, As + (wid << 9));
    GL16(Ab + (size_t)(64 + r0) * lda + k0 + c0, As + 2048 + (wid << 9));
    GL16(Bp + (size_t)r0 * ldb + k0 + c0, Bs + (wid << 9));
    GL16(Bp + (size_t)(64 + r0) * ldb + k0 + c0, Bs + 2048 + (wid << 9));
    __syncthreads();
    sh8 af[4], bfr[4];
#pragma unroll
    for (int f = 0; f < 4; ++f) {
      af[f]  = *(const sh8*)(As + (wr + f * 16 + lr) * 32 + lk);
      bfr[f] = *(const sh8*)(Bs + (wc + f * 16 + lr) * 32 + lk);
    }
#pragma unroll
    for (int i = 0; i < 4; ++i)
#pragma unroll
      for (int j = 0; j < 4; ++j)
        acc[i][j] = __builtin_amdgcn_mfma_f32_16x16x32_bf16(af[i], bfr[j], acc[i][j], 0, 0, 0);
    __syncthreads();
  }

  int cr = (lane >> 4) << 2, cc = lane & 15;
#pragma unroll
  for (int i = 0; i < 4; ++i)
#pragma unroll
    for (int j = 0; j < 4; ++j) {
      size_t cb = (baseA + wr + i * 16 + cr) * (size_t)N + (baseB + wc + j * 16 + cc);
#pragma unroll
      for (int r = 0; r < 4; ++r) {
        float v = acc[i][j][r];
        if constexpr (sizeof(CT) == 2) C[cb + (size_t)r * N] = (CT)f2bf(v);
        else                           C[cb + (size_t)r * N] = v;
      }
    }
}

// ---------------- row LayerNorm (fp32 in) -> bf16 out + INVERSE row L2 norm ----------------
__global__ void ln_rows(const float* __restrict__ X, const float* __restrict__ w,
                        const float* __restrict__ b, u16* __restrict__ Y,
                        float* __restrict__ norms, int C) {
  __shared__ float red[4];
  int row = blockIdx.x;
  const float* x = X + (size_t)row * C;
  int nv = C >> 2;
  float s = 0.f, ss = 0.f;
  for (int i = threadIdx.x; i < nv; i += 256) {
    float4 v = ((const float4*)x)[i];
    s += v.x + v.y + v.z + v.w;
    ss += v.x * v.x + v.y * v.y + v.z * v.z + v.w * v.w;
  }
  s = blk_sum(s, red);
  ss = blk_sum(ss, red);
  float mean = s / C;
  float inv = rsqrtf(fmaxf(ss / C - mean * mean, 0.f) + 1e-5f);
  float nrm = 0.f;
  for (int i = threadIdx.x; i < nv; i += 256) {
    float4 v = ((const float4*)x)[i];
    float4 wv = ((const float4*)w)[i];
    float4 bv = ((const float4*)b)[i];
    float y0 = (v.x - mean) * inv * wv.x + bv.x;
    float y1 = (v.y - mean) * inv * wv.y + bv.y;
    float y2 = (v.z - mean) * inv * wv.z + bv.z;
    float y3 = (v.w - mean) * inv * wv.w + bv.w;
    nrm += y0 * y0 + y1 * y1 + y2 * y2 + y3 * y3;
    us4 o; o.x = f2bf(y0); o.y = f2bf(y1); o.z = f2bf(y2); o.w = f2bf(y3);
    ((us4*)(Y + (size_t)row * C))[i] = o;
  }
  nrm = blk_sum(nrm, red);
  if (threadIdx.x == 0) norms[row] = invnorm(nrm);
}

// ------- eff proto (generic, C wide, optional T1): E = proto + LN(T0[+T1]) -------
__global__ void ln_add_norm(const u16* __restrict__ T0, const u16* __restrict__ T1,
                            const float* __restrict__ P,
                            const float* __restrict__ w, const float* __restrict__ b,
                            u16* __restrict__ E, float* __restrict__ norms, int C) {
  __shared__ float red[4];
  int row = blockIdx.x;
  const us4* t0 = (const us4*)(T0 + (size_t)row * C);
  const us4* t1 = T1 ? (const us4*)(T1 + (size_t)row * C) : nullptr;
  const float* p = P + (size_t)row * C;
  int nv = C >> 2;
  float s = 0.f, ss = 0.f;
  for (int i = threadIdx.x; i < nv; i += 256) {
    us4 v = t0[i];
    float f0 = bf2f(v.x), f1 = bf2f(v.y), f2 = bf2f(v.z), f3 = bf2f(v.w);
    if (t1) {
      us4 v1 = t1[i];
      f0 += bf2f(v1.x); f1 += bf2f(v1.y); f2 += bf2f(v1.z); f3 += bf2f(v1.w);
    }
    s += f0 + f1 + f2 + f3;
    ss += f0 * f0 + f1 * f1 + f2 * f2 + f3 * f3;
  }
  s = blk_sum(s, red);
  ss = blk_sum(ss, red);
  float mean = s / C;
  float inv = rsqrtf(fmaxf(ss / C - mean * mean, 0.f) + 1e-5f);
  float nrm = 0.f;
  for (int i = threadIdx.x; i < nv; i += 256) {
    us4 v = t0[i];
    float f0 = bf2f(v.x), f1 = bf2f(v.y), f2 = bf2f(v.z), f3 = bf2f(v.w);
    if (t1) {
      us4 v1 = t1[i];
      f0 += bf2f(v1.x); f1 += bf2f(v1.y); f2 += bf2f(v1.z); f3 += bf2f(v1.w);
    }
    float4 pv = ((const float4*)p)[i];
    float4 wv = ((const float4*)w)[i];
    float4 bv = ((const float4*)b)[i];
    float y0 = pv.x + (f0 - mean) * inv * wv.x + bv.x;
    float y1 = pv.y + (f1 - mean) * inv * wv.y + bv.y;
    float y2 = pv.z + (f2 - mean) * inv * wv.z + bv.z;
    float y3 = pv.w + (f3 - mean) * inv * wv.w + bv.w;
    nrm += y0 * y0 + y1 * y1 + y2 * y2 + y3 * y3;
    us4 o; o.x = f2bf(y0); o.y = f2bf(y1); o.z = f2bf(y2); o.w = f2bf(y3);
    *(us4*)(E + (size_t)row * C + (i << 2)) = o;
  }
  nrm = blk_sum(nrm, red);
  if (threadIdx.x == 0) norms[row] = invnorm(nrm);
}

// ------- merged eff-proto LN for the three C=1024 protos (z = blockIdx.y) -------
struct Lan3 {
  const u16* T[3];
  const float* P[3]; const float* w[3]; const float* b[3];
  u16* E[3]; float* nr[3]; int M[3];
};
__global__ void lan_many(Lan3 L) {
  __shared__ float red[4];
  int z = blockIdx.y;
  int row = blockIdx.x;
  if (row >= L.M[z]) return;                 // block-uniform: safe w.r.t. syncs
  int i = threadIdx.x;                        // C=1024 -> one us4 per thread
  us4 v = ((const us4*)(L.T[z] + (size_t)row * 1024))[i];
  float f0 = bf2f(v.x), f1 = bf2f(v.y), f2 = bf2f(v.z), f3 = bf2f(v.w);
  float s = blk_sum(f0 + f1 + f2 + f3, red);
  float ss = blk_sum(f0 * f0 + f1 * f1 + f2 * f2 + f3 * f3, red);
  float mean = s * (1.f / 1024.f);
  float inv = rsqrtf(fmaxf(ss * (1.f / 1024.f) - mean * mean, 0.f) + 1e-5f);
  float4 pv = ((const float4*)(L.P[z] + (size_t)row * 1024))[i];
  float4 wv = ((const float4*)L.w[z])[i];
  float4 bv = ((const float4*)L.b[z])[i];
  float y0 = pv.x + (f0 - mean) * inv * wv.x + bv.x;
  float y1 = pv.y + (f1 - mean) * inv * wv.y + bv.y;
  float y2 = pv.z + (f2 - mean) * inv * wv.z + bv.z;
  float y3 = pv.w + (f3 - mean) * inv * wv.w + bv.w;
  us4 o; o.x = f2bf(y0); o.y = f2bf(y1); o.z = f2bf(y2); o.w = f2bf(y3);
  ((us4*)(L.E[z] + (size_t)row * 1024))[i] = o;
  float nrm = blk_sum(y0 * y0 + y1 * y1 + y2 * y2 + y3 * y3, red);
  if (threadIdx.x == 0) L.nr[z][row] = invnorm(nrm);
}

// ---------------- INVERSE row L2 norm of a bf16 matrix ----------------
__global__ void rownorm_bf(const u16* __restrict__ X, float* __restrict__ norms, int C) {
  __shared__ float red[4];
  int row = blockIdx.x;
  const us4* x = (const us4*)(X + (size_t)row * C);
  int nv = C >> 2;
  float nrm = 0.f;
  for (int i = threadIdx.x; i < nv; i += 256) {
    us4 v = x[i];
    float a = bf2f(v.x), b = bf2f(v.y), c = bf2f(v.z), d = bf2f(v.w);
    nrm += a * a + b * b + c * c + d * d;
  }
  nrm = blk_sum(nrm, red);
  if (threadIdx.x == 0) norms[row] = invnorm(nrm);
}

// ---- SPL epilogue core (stacked-block G rows of width 2C); rr/cn are INVERSE norms ----
__device__ __forceinline__ void epi4(const u16* gr, int C, int c, float rr,
                                     const float* bias, const float* gate,
                                     const float* cn, float* o) {
  us4 cv = *(const us4*)(gr + c);
  us4 dv = *(const us4*)(gr + C + c);
  float4 bv = *(const float4*)(bias + c);
  float4 gv = *(const float4*)(gate + c);
  float4 nv = *(const float4*)(cn + c);
  float cf[4] = {bf2f(cv.x), bf2f(cv.y), bf2f(cv.z), bf2f(cv.w)};
  float df[4] = {bf2f(dv.x), bf2f(dv.y), bf2f(dv.z), bf2f(dv.w)};
  float bb[4] = {bv.x, bv.y, bv.z, bv.w};
  float gg[4] = {gv.x, gv.y, gv.z, gv.w};
  float nn[4] = {nv.x, nv.y, nv.z, nv.w};
#pragma unroll
  for (int j = 0; j < 4; ++j) {
    float sc = df[j] * (rr * nn[j]);
    o[j] = (cf[j] + bb[j]) * fmaxf(sc - gg[j], 0.f);
  }
}

// --------- fused qkv SPL epilogue + RoPE, one block per row ----------
__global__ void spl_rope_row(const u16* __restrict__ G, const float* __restrict__ bias,
                             const float* __restrict__ gate, const float* __restrict__ rn,
                             const float* __restrict__ cn, const float* __restrict__ CT_,
                             const float* __restrict__ ST_, u16* __restrict__ MQ) {
  int r = blockIdx.x;
  int s = r & 2047;
  const u16* gr = G + (size_t)r * 6144;
  u16* outr = MQ + (size_t)r * 3072;
  float rr = rn[r];
  int t = threadIdx.x;

  int qk = (t >> 7);              // 0 = q, 1 = k
  int c = qk * 1024 + ((t & 127) << 2);
  int d = c - qk * 1024;
  float a0[4], a1[4];
  epi4(gr, 3072, c, rr, bias, gate, cn, a0);
  epi4(gr, 3072, c + 512, rr, bias, gate, cn, a1);
  const float* ct = CT_ + (size_t)s * 1024;
  const float* st = ST_ + (size_t)s * 1024;
  float4 c0 = *(const float4*)(ct + d);
  float4 s0 = *(const float4*)(st + d);
  float4 c1 = *(const float4*)(ct + d + 512);
  float4 s1 = *(const float4*)(st + d + 512);
  float cc0[4] = {c0.x, c0.y, c0.z, c0.w}, ss0[4] = {s0.x, s0.y, s0.z, s0.w};
  float cc1[4] = {c1.x, c1.y, c1.z, c1.w}, ss1[4] = {s1.x, s1.y, s1.z, s1.w};
  us4 o0, o1;
  o0.x = f2bf(a0[0] * cc0[0] - a1[0] * ss0[0]);
  o0.y = f2bf(a0[1] * cc0[1] - a1[1] * ss0[1]);
  o0.z = f2bf(a0[2] * cc0[2] - a1[2] * ss0[2]);
  o0.w = f2bf(a0[3] * cc0[3] - a1[3] * ss0[3]);
  o1.x = f2bf(a1[0] * cc1[0] + a0[0] * ss1[0]);
  o1.y = f2bf(a1[1] * cc1[1] + a0[1] * ss1[1]);
  o1.z = f2bf(a1[2] * cc1[2] + a0[2] * ss1[2]);
  o1.w = f2bf(a1[3] * cc1[3] + a0[3] * ss1[3]);
  *(us4*)(outr + c) = o0;
  *(us4*)(outr + c + 512) = o1;

  int cv_ = 2048 + (t << 2);
  float vv[4];
  epi4(gr, 3072, cv_, rr, bias, gate, cn, vv);
  us4 ov; ov.x = f2bf(vv[0]); ov.y = f2bf(vv[1]); ov.z = f2bf(vv[2]); ov.w = f2bf(vv[3]);
  *(us4*)(outr + cv_) = ov;
}

// --------- fused f1 SPL epilogue (relu) + INVERSE row norm of h ---------
__global__ void spl_f1_row(const u16* __restrict__ G, const float* __restrict__ bias,
                           const float* __restrict__ gate, const float* __restrict__ rn,
                           const float* __restrict__ cn, u16* __restrict__ H,
                           float* __restrict__ rn_h) {
  __shared__ float red[4];
  int r = blockIdx.x;
  const u16* gr = G + (size_t)r * 8192;
  u16* hr = H + (size_t)r * 4096;
  float rr = rn[r];
  float nrm = 0.f;
  for (int c = threadIdx.x << 2; c < 4096; c += 1024) {
    float o[4];
    epi4(gr, 4096, c, rr, bias, gate, cn, o);
#pragma unroll
    for (int j = 0; j < 4; ++j) {
      o[j] = fmaxf(o[j], 0.f);
      nrm += o[j] * o[j];
    }
    us4 ov; ov.x = f2bf(o[0]); ov.y = f2bf(o[1]); ov.z = f2bf(o[2]); ov.w = f2bf(o[3]);
    *(us4*)(hr + c) = ov;
  }
  nrm = blk_sum(nrm, red);
  if (threadIdx.x == 0) rn_h[r] = invnorm(nrm);
}

// --- fused o SPL + residual -> X1 (fp32), then LN2 -> bf16 + inverse rn_ffn ---
__global__ void spl_o_ln_row(const u16* __restrict__ G, const float* __restrict__ bias,
                             const float* __restrict__ gate, const float* __restrict__ rn,
                             const float* __restrict__ cn, const float* __restrict__ xres,
                             const float* __restrict__ lw, const float* __restrict__ lb,
                             float* __restrict__ X1, u16* __restrict__ Y,
                             float* __restrict__ rn_ffn) {
  __shared__ float red[4];
  int r = blockIdx.x;
  int c = threadIdx.x << 2;
  const u16* gr = G + (size_t)r * 2048;
  float o[4];
  epi4(gr, 1024, c, rn[r], bias, gate, cn, o);
  float4 rv = *(const float4*)(xres + (size_t)r * 1024 + c);
  o[0] += rv.x; o[1] += rv.y; o[2] += rv.z; o[3] += rv.w;
  float4 xo = {o[0], o[1], o[2], o[3]};
  *(float4*)(X1 + (size_t)r * 1024 + c) = xo;
  float s = o[0] + o[1] + o[2] + o[3];
  float ss = o[0] * o[0] + o[1] * o[1] + o[2] * o[2] + o[3] * o[3];
  s = blk_sum(s, red);
  ss = blk_sum(ss, red);
  float mean = s * (1.f / 1024.f);
  float inv = rsqrtf(fmaxf(ss * (1.f / 1024.f) - mean * mean, 0.f) + 1e-5f);
  float4 wv = *(const float4*)(lw + c);
  float4 bv = *(const float4*)(lb + c);
  float ww[4] = {wv.x, wv.y, wv.z, wv.w}, bb[4] = {bv.x, bv.y, bv.z, bv.w};
  float nrm = 0.f;
  us4 ov;
  u16* op = (u16*)&ov;
#pragma unroll
  for (int j = 0; j < 4; ++j) {
    float y = (o[j] - mean) * inv * ww[j] + bb[j];
    nrm += y * y;
    op[j] = f2bf(y);
  }
  *(us4*)(Y + (size_t)r * 1024 + c) = ov;
  nrm = blk_sum(nrm, red);
  if (threadIdx.x == 0) rn_ffn[r] = invnorm(nrm);
}

// ------ final SPL epilogue: bf16 split-K partial pair + residual -> fp32 out ------
__global__ void spl_epi_p(const u16* __restrict__ G0, const u16* __restrict__ G1,
                          const float* __restrict__ bias, const float* __restrict__ gate,
                          const float* __restrict__ rn, const float* __restrict__ cn,
                          const float* __restrict__ resid, float* __restrict__ out) {
  int r = blockIdx.x;
  int c = threadIdx.x << 2;
  size_t rowb = (size_t)r * 2048;
  us4 c0 = *(const us4*)(G0 + rowb + c);
  us4 c1 = *(const us4*)(G1 + rowb + c);
  us4 d0 = *(const us4*)(G0 + rowb + 1024 + c);
  us4 d1 = *(const us4*)(G1 + rowb + 1024 + c);
  float4 bv = *(const float4*)(bias + c);
  float4 gv = *(const float4*)(gate + c);
  float4 nv = *(const float4*)(cn + c);
  float4 rv = *(const float4*)(resid + (size_t)r * 1024 + c);
  float rr = rn[r];
  float cf[4] = {bf2f(c0.x) + bf2f(c1.x), bf2f(c0.y) + bf2f(c1.y),
                 bf2f(c0.z) + bf2f(c1.z), bf2f(c0.w) + bf2f(c1.w)};
  float df[4] = {bf2f(d0.x) + bf2f(d1.x), bf2f(d0.y) + bf2f(d1.y),
                 bf2f(d0.z) + bf2f(d1.z), bf2f(d0.w) + bf2f(d1.w)};
  float bb[4] = {bv.x, bv.y, bv.z, bv.w};
  float gg[4] = {gv.x, gv.y, gv.z, gv.w};
  float nn[4] = {nv.x, nv.y, nv.z, nv.w};
  float re[4] = {rv.x, rv.y, rv.z, rv.w};
  float4 ov;
  float* op = (float*)&ov;
#pragma unroll
  for (int j = 0; j < 4; ++j) {
    float sc = df[j] * (rr * nn[j]);
    op[j] = (cf[j] + bb[j]) * fmaxf(sc - gg[j], 0.f) + re[j];
  }
  *(float4*)(out + (size_t)r * 1024 + c) = ov;
}

// ---------------- V transpose (bf16 m_qkv -> VT[b][d][s]) ----------------
__global__ void vtrans(const u16* __restrict__ MQ, u16* __restrict__ VT) {
  __shared__ u16 tile[32][33];
  int b = blockIdx.z;
  int s0 = blockIdx.x << 5, d0 = blockIdx.y << 5;
  int tx = threadIdx.x, ty = threadIdx.y;
  for (int r = ty; r < 32; r += 8)
    tile[r][tx] = MQ[((size_t)(b * 2048 + s0 + r)) * 3072 + 2048 + d0 + tx];
  __syncthreads();
  for (int r = ty; r < 32; r += 8)
    VT[(size_t)b * 1024 * 2048 + (size_t)(d0 + r) * 2048 + s0 + tx] = tile[tx][r];
}

// ---- causal softmax over [2][2048][2048] bf16 scores, scale 1/32 -> bf16 P ----
__global__ void softmax_causal(const u16* __restrict__ S, u16* __restrict__ P) {
  __shared__ float red[4];
  int b = blockIdx.x >> 11;
  int q = blockIdx.x & 2047;
  const u16* row = S + ((size_t)b << 22) + (size_t)q * 2048;
  u16* prow = P + ((size_t)b << 22) + (size_t)q * 2048;
  int nv = q + 1;
  int wcap = ((q >> 7) + 1) << 7;
  int base = threadIdx.x * 8;
  float e[8];
  float m = -3.4e38f;
  float xv[8];
  bool live = base < nv;
  if (live) {
    us4 a = *(const us4*)(row + base);
    us4 bq = *(const us4*)(row + base + 4);
    xv[0] = bf2f(a.x); xv[1] = bf2f(a.y); xv[2] = bf2f(a.z); xv[3] = bf2f(a.w);
    xv[4] = bf2f(bq.x); xv[5] = bf2f(bq.y); xv[6] = bf2f(bq.z); xv[7] = bf2f(bq.w);
#pragma unroll
    for (int j = 0; j < 8; ++j) {
      xv[j] *= 0.03125f;
      if (base + j < nv) m = fmaxf(m, xv[j]);
    }
  }
  m = blk_max(m, red);
  float ssum = 0.f;
#pragma unroll
  for (int j = 0; j < 8; ++j) {
    e[j] = (live && base + j < nv) ? __expf(xv[j] - m) : 0.f;
    ssum += e[j];
  }
  ssum = blk_sum(ssum, red);
  float invs = 1.f / ssum;
  if (base < wcap) {
    us4 o;
    o.x = f2bf(e[0] * invs); o.y = f2bf(e[1] * invs);
    o.z = f2bf(e[2] * invs); o.w = f2bf(e[3] * invs);
    ((us4*)prow)[threadIdx.x * 2] = o;
    o.x = f2bf(e[4] * invs); o.y = f2bf(e[5] * invs);
    o.z = f2bf(e[6] * invs); o.w = f2bf(e[7] * invs);
    ((us4*)prow)[threadIdx.x * 2 + 1] = o;
  }
}

// =============================== launcher ===============================
extern "C" void kernel_launch(void* const* d_in, const int* in_sizes, int n_in,
                              void* d_out, int out_size, void* d_ws, size_t ws_size,
                              hipStream_t stream) {
  (void)in_sizes;
  const float* x         = (const float*)d_in[0];
  const float* cosT      = (const float*)d_in[1];
  const float* sinT      = (const float*)d_in[2];
  const float* ln1_w     = (const float*)d_in[3];
  const float* ln1_b     = (const float*)d_in[4];
  const float* ln2_w     = (const float*)d_in[5];
  const float* ln2_b     = (const float*)d_in[6];
  const float* qkv_mu    = (const float*)d_in[7];
  const float* qkv_proto = (const float*)d_in[8];
  const float* qkv_bias  = (const float*)d_in[9];
  const float* qkv_gate  = (const float*)d_in[10];
  const float* o_mu      = (const float*)d_in[11];
  const float* o_proto   = (const float*)d_in[12];
  const float* o_bias    = (const float*)d_in[13];
  const float* o_gate    = (const float*)d_in[14];
  const float* f1_mu     = (const float*)d_in[15];
  const float* f1_proto  = (const float*)d_in[16];
  const float* f1_bias   = (const float*)d_in[17];
  const float* f1_gate   = (const float*)d_in[18];
  const float* f2_mu     = (const float*)d_in[19];
  const float* f2_proto  = (const float*)d_in[20];
  const float* f2_bias   = (const float*)d_in[21];
  const float* f2_gate   = (const float*)d_in[22];
  const float* pt_qkv    = (const float*)d_in[23];
  const float* pt_o      = (const float*)d_in[24];
  const float* pt_f1     = (const float*)d_in[25];
  const float* pt_f2     = (const float*)d_in[26];
  const float* pln_qkv_w = (const float*)d_in[27];
  const float* pln_qkv_b = (const float*)d_in[28];
  const float* pln_o_w   = (const float*)d_in[29];
  const float* pln_o_b   = (const float*)d_in[30];
  const float* pln_f1_w  = (const float*)d_in[31];
  const float* pln_f1_b  = (const float*)d_in[32];
  const float* pln_f2_w  = (const float*)d_in[33];
  const float* pln_f2_b  = (const float*)d_in[34];
  const float* prev_qkv  = (const float*)d_in[35];
  const float* prev_o    = (const float*)d_in[36];
  const float* prev_f1   = (const float*)d_in[37];
  const float* prev_f2   = (const float*)d_in[38];

  const long D = 1024, TD = 3072, FD = 4096, R = 4096;

  char* W = (char*)d_ws;
  size_t off = 0;
  auto alloc = [&](size_t bytes) {
    void* p = W + off;
    off = (off + bytes + 255) & ~(size_t)255;
    return p;
  };
  char* GOUT = (char*)alloc(67108864);   // staging / G / scores+P / f2 partials
  u16*  RC   = (u16*)alloc(33554432);    // proto T / m_qkv / h
  u16*  wq   = (u16*)alloc(2 * TD * D * 2);   // [mu; eff] stacked along N
  u16*  wo   = (u16*)alloc(2 * D * D * 2);
  u16*  wf1  = (u16*)alloc(2 * FD * D * 2);
  u16*  wf2  = (u16*)alloc(2 * D * FD * 2);
  float* X1  = (float*)alloc(R * D * 4);
  u16*  P1   = (u16*)alloc(R * D * 2);        // attn_in / ffn_in bf16
  u16*  VT   = (u16*)alloc(2 * D * 2048 * 2);
  u16*  AOB  = (u16*)alloc(R * D * 2);
  float* pnq     = (float*)alloc(TD * 4);
  float* pno     = (float*)alloc(D * 4);
  float* pnf1    = (float*)alloc(FD * 4);
  float* pnf2    = (float*)alloc(D * 4);
  float* rn_ain  = (float*)alloc(R * 4);
  float* rn_aout = (float*)alloc(R * 4);
  float* rn_ffn  = (float*)alloc(R * 4);
  float* rn_h    = (float*)alloc(R * 4);
  size_t need = off;

  if (n_in < 39 || need > ws_size) {
    long n = out_size;
    fillv<<<dim3((unsigned)((n + 255) / 256)), 256, 0, stream>>>((float*)d_out, n, 12345.0f);
    return;
  }

  // overlays inside GOUT (staging packed 0..64MB, all dead before phase 2)
  u16* SA  = (u16*)GOUT;                      // prev f1/qkv/o @ 0, 8MB, 16MB
  u16* SB  = (u16*)(GOUT + 18874368);         // pt f1/qkv/o @ 18MB + 2MB stride
  u16* PF2 = (u16*)(GOUT + 25165824);         // prev_f2 @ 24MB (8MB)
  u16* TF2 = (u16*)(GOUT + 33554432);         // pt_f2   @ 32MB (32MB)
  u16* SCORESB = (u16*)GOUT;                  // [2][2048][2048] bf16 = 16 MiB
  u16* PB = (u16*)(GOUT + 16777216);          // [2][2048][2048] bf16 = 16 MiB

  // ---- phase 1: ALL weight conversions in ONE exact-grid launch ----
  {
    CvtN12 c;
    c.s[0]  = prev_f1;  c.d[0]  = SA;            c.n4[0]  = (FD * D) >> 2;
    c.s[1]  = prev_qkv; c.d[1]  = SA + 4194304;  c.n4[1]  = (TD * D) >> 2;
    c.s[2]  = prev_o;   c.d[2]  = SA + 8388608;  c.n4[2]  = (D * D) >> 2;
    c.s[3]  = pt_f1;    c.d[3]  = SB;            c.n4[3]  = (D * D) >> 2;
    c.s[4]  = pt_qkv;   c.d[4]  = SB + 1048576;  c.n4[4]  = (D * D) >> 2;
    c.s[5]  = pt_o;     c.d[5]  = SB + 2097152;  c.n4[5]  = (D * D) >> 2;
    c.s[6]  = qkv_mu;   c.d[6]  = wq;            c.n4[6]  = (TD * D) >> 2;
    c.s[7]  = f1_mu;    c.d[7]  = wf1;           c.n4[7]  = (FD * D) >> 2;
    c.s[8]  = o_mu;     c.d[8]  = wo;            c.n4[8]  = (D * D) >> 2;
    c.s[9]  = f2_mu;    c.d[9]  = wf2;           c.n4[9]  = (D * FD) >> 2;
    c.s[10] = prev_f2;  c.d[10] = PF2;           c.n4[10] = (D * FD) >> 2;
    c.s[11] = pt_f2;    c.d[11] = TF2;           c.n4[11] = ((long)FD * FD) >> 2;
    int ofs = 0;
    for (int k = 0; k < 12; ++k) {
      c.bofs[k] = ofs;
      ofs += (int)((c.n4[k] + 255) >> 8);
    }
    c.bofs[12] = ofs;                            // 44032 blocks total, zero waste
    cvt_many<<<dim3((unsigned)ofs), 256, 0, stream>>>(c);
  }
  // batched qkv/o/f1 proto GEMMs: z=0 f1(M=4096), z=1 qkv(3072), z=2 o(1024)
  {
    long Mz = 4096L | (3072L << 16) | (1024L << 32);
    gemm_bt<u16><<<dim3(32, 8, 3), 256, 0, stream>>>(
        SA, SB, RC, 4096, 1024, 1024, 1024, 1024, 5, 4194304, Mz, 4194304);
  }
  // merged eff-proto LN (three C=1024 protos)
  {
    Lan3 L;
    L.T[0] = RC;           L.P[0] = f1_proto;  L.w[0] = pln_f1_w;  L.b[0] = pln_f1_b;
    L.E[0] = wf1 + (size_t)FD * D;  L.nr[0] = pnf1;  L.M[0] = 4096;
    L.T[1] = RC + 4194304; L.P[1] = qkv_proto; L.w[1] = pln_qkv_w; L.b[1] = pln_qkv_b;
    L.E[1] = wq + (size_t)TD * D;   L.nr[1] = pnq;   L.M[1] = 3072;
    L.T[2] = RC + 8388608; L.P[2] = o_proto;   L.w[2] = pln_o_w;   L.b[2] = pln_o_b;
    L.E[2] = wo + (size_t)D * D;    L.nr[2] = pno;   L.M[2] = 1024;
    lan_many<<<dim3(4096, 3), 256, 0, stream>>>(L);
  }
  // f2 proto: split-K x2 GEMM (after lan_many has consumed RC), LN-add
  gemm_bt<u16><<<dim3(8, 32, 2), 256, 0, stream>>>(
      PF2, TF2, RC, 1024, 4096, 4096, 4096, 4096, 1, 0, 0, 0);
  ln_add_norm<<<1024, 256, 0, stream>>>(RC, RC + 4194304, f2_proto, pln_f2_w, pln_f2_b,
                                        wf2 + (size_t)D * FD, pnf2, 4096);

  // ---- phase 2: attention input LN + qkv GEMM (gemm256, 2 blocks/CU) + RoPE epi ----
  ln_rows<<<4096, 256, 0, stream>>>(x, ln1_w, ln1_b, P1, rn_ain, 1024);
  gemm256<u16><<<dim3(16, 24), 512, 65536, stream>>>(
      P1, wq, (u16*)GOUT, 4096, 6144, 1024, 1024, 1024, 0);
  spl_rope_row<<<4096, 256, 0, stream>>>(
      (u16*)GOUT, qkv_bias, qkv_gate, rn_ain, pnq, cosT, sinT, RC);

  // ---- phase 3: attention (batched, bf16 scores) ----
  vtrans<<<dim3(64, 32, 2), dim3(32, 8), 0, stream>>>(RC, VT);
  gemm_bt<u16><<<dim3(136, 1, 2), 256, 0, stream>>>(
      RC, RC + 1024, SCORESB, 2048, 2048, 1024, 3072, 3072,
      3, 2048L * 3072, 2048L * 3072, 1L << 22);
  softmax_causal<<<4096, 256, 0, stream>>>(SCORESB, PB);
  gemm_bt<u16><<<dim3(16, 8, 2), 256, 0, stream>>>(
      PB, VT, AOB, 2048, 1024, 2048, 2048, 2048,
      4, 1L << 22, 1024L * 2048, 2048L * 1024);
  rownorm_bf<<<4096, 256, 0, stream>>>(AOB, rn_aout, 1024);

  // ---- phase 4: fused o SPL + residual + LN2 ----
  gemm_bt<u16><<<dim3(32, 16, 1), 256, 0, stream>>>(
      AOB, wo, (u16*)GOUT, 4096, 2048, 1024, 1024, 1024, 0, 0, 0, 0);
  spl_o_ln_row<<<4096, 256, 0, stream>>>(
      (u16*)GOUT, o_bias, o_gate, rn_aout, pno, x, ln2_w, ln2_b, X1, P1, rn_ffn);

  // ---- phase 5: FFN ----
  gemm256<u16><<<dim3(16, 32), 512, 65536, stream>>>(
      P1, wf1, (u16*)GOUT, 4096, 8192, 1024, 1024, 1024, 0);
  spl_f1_row<<<4096, 256, 0, stream>>>(
      (u16*)GOUT, f1_bias, f1_gate, rn_ffn, pnf1, RC, rn_h);      // h -> RC
  gemm256<u16><<<dim3(16, 8, 2), 512, 65536, stream>>>(
      RC, wf2, (u16*)GOUT, 4096, 2048, 4096, 4096, 4096, 2048);
  spl_epi_p<<<4096, 256, 0, stream>>>(
      (u16*)GOUT, (u16*)GOUT + 8388608, f2_bias, f2_gate, rn_h, pnf2,
      X1, (float*)d_out);
}

// Round 14
// 555.897 us; speedup vs baseline: 1.0114x; 1.0114x over previous
//
#include <hip/hip_runtime.h>
#include <cstdint>

typedef unsigned short u16;
typedef __attribute__((ext_vector_type(8))) short sh8;   // 8 bf16 (4 VGPRs)
typedef __attribute__((ext_vector_type(4))) float f32x4;

struct __align__(8) us4 { u16 x, y, z, w; };

__device__ __forceinline__ u16 f2bf(float f) {
  unsigned u = __float_as_uint(f);
  u += 0x7FFFu + ((u >> 16) & 1u);   // RNE
  return (u16)(u >> 16);
}
__device__ __forceinline__ float bf2f(u16 h) {
  return __uint_as_float((unsigned)h << 16);
}
// inverse norm: 1/max(sqrt(x),1e-12) == min(rsqrt(x),1e12)
__device__ __forceinline__ float invnorm(float nrm) {
  return fminf(rsqrtf(nrm), 1e12f);
}

// ---------------- block reductions (blockDim.x == 256) ----------------
__device__ __forceinline__ float blk_sum(float v, float* red) {
#pragma unroll
  for (int o = 32; o; o >>= 1) v += __shfl_xor(v, o);
  __syncthreads();
  if ((threadIdx.x & 63) == 0) red[threadIdx.x >> 6] = v;
  __syncthreads();
  return red[0] + red[1] + red[2] + red[3];
}
__device__ __forceinline__ float blk_max(float v, float* red) {
#pragma unroll
  for (int o = 32; o; o >>= 1) v = fmaxf(v, __shfl_xor(v, o));
  __syncthreads();
  if ((threadIdx.x & 63) == 0) red[threadIdx.x >> 6] = v;
  __syncthreads();
  return fmaxf(fmaxf(red[0], red[1]), fmaxf(red[2], red[3]));
}

__global__ void fillv(float* __restrict__ o, long n, float v) {
  long i = (long)blockIdx.x * blockDim.x + threadIdx.x;
  if (i < n) o[i] = v;
}

// ------- merged fp32 -> bf16, EXACT 1-D grid via block-offset prefix table -------
struct CvtN12 {
  const float* s[12];
  u16* d[12];
  long n4[12];
  int bofs[13];   // block-offset prefix; grid.x == bofs[12]
};
__global__ void cvt_many(CvtN12 c) {
  int blk = blockIdx.x;
  int z = 0;
  while (z < 11 && blk >= c.bofs[z + 1]) ++z;   // block-uniform scalar scan
  long i = (long)(blk - c.bofs[z]) * blockDim.x + threadIdx.x;
  if (i >= c.n4[z]) return;
  float4 v = ((const float4*)c.s[z])[i];
  us4 o; o.x = f2bf(v.x); o.y = f2bf(v.y); o.z = f2bf(v.z); o.w = f2bf(v.w);
  ((us4*)c.d[z])[i] = o;
}

#define GL16(gp, lp)                                                        \
  __builtin_amdgcn_global_load_lds(                                         \
      (const __attribute__((address_space(1))) void*)(gp),                  \
      (__attribute__((address_space(3))) void*)(lp), 16, 0, 0)

// ---- gemm256 body (256x256 tile, 8 waves, 4-slot 128KiB ring, counted vmcnt,
//      XOR bank-swizzle, T5 setprio) — round-10/12 verified configuration ----
#define G256_PROLOG()                                                          \
  extern __shared__ u16 lds[];   /* 4 slots x (A 8192 + B 8192) u16 = 128KiB */\
  int tid = threadIdx.x;                                                       \
  int wid = tid >> 6, lane = tid & 63;                                         \
  int wm = wid >> 2, wn = wid & 3;                                             \
  int bm = blockIdx.x, bn = blockIdx.y;                                        \
  int k0s = 0, nt;                                                             \
  if (kchunk) {                                                                \
    k0s = blockIdx.z * kchunk;                                                 \
    nt = kchunk >> 5;                                                          \
  } else {                                                                     \
    nt = K >> 5;                                                               \
  }                                                                            \
  const size_t baseArow = (size_t)bm * 256;                                    \
  const size_t baseBrow = (size_t)bn * 256;                                    \
  int ci = (wid << 6) + lane;                                                  \
  int rowS = ci >> 2;                                                          \
  int kcS = (ci ^ (ci >> 3)) & 3;                                              \
  const u16* gA0 = A + (baseArow + rowS) * lda + k0s + kcS * 8;                \
  const u16* gA1 = gA0 + (size_t)128 * lda;                                    \
  const u16* gB0 = B + (baseBrow + rowS) * ldb + k0s + kcS * 8;                \
  const u16* gB1 = gB0 + (size_t)128 * ldb;                                    \
  u16* dBase = lds + (wid << 9);                                               \
  int l15 = lane & 15, l4 = lane >> 4;                                         \
  int aoff[8], boff[4];                                                        \
  _Pragma("unroll") for (int fr = 0; fr < 8; ++fr) {                           \
    int by = (wm * 128 + fr * 16 + l15) * 64 + l4 * 16;                        \
    aoff[fr] = (by ^ (((by >> 7) & 3) << 4)) >> 1;                             \
  }                                                                            \
  _Pragma("unroll") for (int fc = 0; fc < 4; ++fc) {                           \
    int by = (wn * 64 + fc * 16 + l15) * 64 + l4 * 16;                         \
    boff[fc] = 8192 + ((by ^ (((by >> 7) & 3) << 4)) >> 1);                    \
  }                                                                            \
  f32x4 acc[8][4];                                                             \
  const f32x4 zf = {0.f, 0.f, 0.f, 0.f};                                       \
  _Pragma("unroll") for (int i = 0; i < 8; ++i)                                \
    _Pragma("unroll") for (int j = 0; j < 4; ++j) acc[i][j] = zf;

#define STAGE256(ts)                                                  \
  do {                                                                \
    int ss_ = (ts) & 3;                                               \
    int kk_ = (ts) << 5;                                              \
    u16* d_ = dBase + ss_ * 16384;                                    \
    GL16(gA0 + kk_, d_);                                              \
    GL16(gA1 + kk_, d_ + 4096);                                       \
    GL16(gB0 + kk_, d_ + 8192);                                       \
    GL16(gB1 + kk_, d_ + 12288);                                      \
  } while (0)

#define G256_KLOOP()                                                           \
  STAGE256(0);                                                                 \
  STAGE256(1);                                                                 \
  STAGE256(2);                                                                 \
  asm volatile("s_waitcnt vmcnt(8)" ::: "memory");                             \
  __builtin_amdgcn_s_barrier();                                                \
  __builtin_amdgcn_sched_barrier(0);                                           \
  for (int t = 0; t < nt; ++t) {                                               \
    int ts = t + 3;                                                            \
    if (ts < nt) STAGE256(ts);                                                 \
    const u16* sl = lds + (t & 3) * 16384;                                     \
    sh8 af[8], bfv[4];                                                         \
    _Pragma("unroll") for (int fc = 0; fc < 4; ++fc)                           \
        bfv[fc] = *(const sh8*)(sl + boff[fc]);                                \
    _Pragma("unroll") for (int fr = 0; fr < 8; ++fr)                           \
        af[fr] = *(const sh8*)(sl + aoff[fr]);                                 \
    __builtin_amdgcn_s_setprio(1);                                             \
    _Pragma("unroll") for (int fr = 0; fr < 8; ++fr)                           \
      _Pragma("unroll") for (int fc = 0; fc < 4; ++fc)                         \
        acc[fr][fc] = __builtin_amdgcn_mfma_f32_16x16x32_bf16(                 \
            af[fr], bfv[fc], acc[fr][fc], 0, 0, 0);                            \
    __builtin_amdgcn_s_setprio(0);                                             \
    int rem = nt - 2 - t;                                                      \
    if (rem >= 2)      asm volatile("s_waitcnt vmcnt(8)" ::: "memory");        \
    else if (rem == 1) asm volatile("s_waitcnt vmcnt(4)" ::: "memory");        \
    else if (rem == 0) asm volatile("s_waitcnt vmcnt(0)" ::: "memory");        \
    if (t < nt - 1) {                                                          \
      __builtin_amdgcn_s_barrier();                                            \
      __builtin_amdgcn_sched_barrier(0);                                       \
    }                                                                          \
  }

// ================= plain 256x256 pipelined GEMM: C = A @ B^T =================
// kchunk > 0: split-K over blockIdx.z (C += z*M*N).
template <typename CT>
__global__ __launch_bounds__(512, 1) void gemm256(
    const u16* __restrict__ A, const u16* __restrict__ B, CT* __restrict__ C,
    int M, int N, int K, int lda, int ldb, int kchunk) {
  if (kchunk) C += (size_t)blockIdx.z * M * (size_t)N;
  G256_PROLOG();
  G256_KLOOP();
  // C/D layout (m89): col = lane&15, row = (lane>>4)*4 + reg
  int cr = l4 << 2, cc = l15;
  const size_t rbase = baseArow + wm * 128 + cr;
  const size_t cbase = baseBrow + wn * 64 + cc;
#pragma unroll
  for (int fr = 0; fr < 8; ++fr)
#pragma unroll
    for (int fc = 0; fc < 4; ++fc) {
      size_t cb = (rbase + fr * 16) * (size_t)N + cbase + fc * 16;
#pragma unroll
      for (int r = 0; r < 4; ++r) {
        float v = acc[fr][fc][r];
        if constexpr (sizeof(CT) == 2) C[cb + (size_t)r * N] = (CT)f2bf(v);
        else                           C[cb + (size_t)r * N] = v;
      }
    }
}

// ---------------- bf16 GEMM: C[M,N] = A[M,K] @ B[N,K]^T (128^2, m97) ----------------
// mode 0: plain | 1: split-K z | 2: batched z | 3: batched + causal tri |
// mode 4: batched + causal K-cap | 5: multi-M batched (Mz packed in zsB)
template <typename CT>
__global__ __launch_bounds__(256, 2) void gemm_bt(
    const u16* __restrict__ A, const u16* __restrict__ B, CT* __restrict__ C,
    int M, int N, int K, int lda, int ldb,
    int mode, long zsA, long zsB, long zsC) {
  int bm, bn;
  int z = blockIdx.z;
  if (mode == 3) {
    int t = blockIdx.x;
    int m = (int)floorf((sqrtf(8.f * t + 1.f) - 1.f) * 0.5f);
    while ((m + 1) * (m + 2) / 2 <= t) ++m;
    while (m * (m + 1) / 2 > t) --m;
    bm = m; bn = t - m * (m + 1) / 2;
  } else {
    bm = blockIdx.x; bn = blockIdx.y;
  }
  int k0s = 0, k0e = K;
  if (mode == 1) {
    int kc = K / gridDim.z;
    k0s = z * kc; k0e = k0s + kc;
    C += (size_t)z * M * (size_t)N;
  } else if (mode == 2 || mode == 3) {
    A += (size_t)z * zsA; B += (size_t)z * zsB; C += (size_t)z * zsC;
  } else if (mode == 4) {
    A += (size_t)z * zsA; B += (size_t)z * zsB; C += (size_t)z * zsC;
    k0e = (bm + 1) * 128;
  } else if (mode == 5) {
    int Mz = (int)((zsB >> (z * 16)) & 0xFFFF);
    if (bm * 128 >= Mz) return;
    A += (size_t)z * zsA; B += (size_t)z * 1048576; C += (size_t)z * zsC;
  }

  __shared__ __align__(16) u16 As[128 * 32];
  __shared__ __align__(16) u16 Bs[128 * 32];
  int tid = threadIdx.x, wid = tid >> 6, lane = tid & 63;
  int wr = (wid >> 1) << 6, wc = (wid & 1) << 6;
  int lr = lane & 15, lk = (lane >> 4) << 3;

  f32x4 acc[4][4];
  const f32x4 zf = {0.f, 0.f, 0.f, 0.f};
#pragma unroll
  for (int i = 0; i < 4; ++i)
#pragma unroll
    for (int j = 0; j < 4; ++j) acc[i][j] = zf;

  int r0 = tid >> 2, c0 = (tid & 3) << 3;
  const size_t baseA = (size_t)bm * 128, baseB = (size_t)bn * 128;
  const u16* Ab = A + baseA * lda;
  const u16* Bp = B + baseB * ldb;

  for (int k0 = k0s; k0 < k0e; k0 += 32) {
    GL16(Ab + (size_t)r0 * lda + k0 + c0, As + (wid << 9));
    GL16(Ab + (size_t)(64 + r0) * lda + k0 + c0, As + 2048 + (wid << 9));
    GL16(Bp + (size_t)r0 * ldb + k0 + c0, Bs + (wid << 9));
    GL16(Bp + (size_t)(64 + r0) * ldb + k0 + c0, Bs + 2048 + (wid << 9));
    __syncthreads();
    sh8 af[4], bfr[4];
#pragma unroll
    for (int f = 0; f < 4; ++f) {
      af[f]  = *(const sh8*)(As + (wr + f * 16 + lr) * 32 + lk);
      bfr[f] = *(const sh8*)(Bs + (wc + f * 16 + lr) * 32 + lk);
    }
#pragma unroll
    for (int i = 0; i < 4; ++i)
#pragma unroll
      for (int j = 0; j < 4; ++j)
        acc[i][j] = __builtin_amdgcn_mfma_f32_16x16x32_bf16(af[i], bfr[j], acc[i][j], 0, 0, 0);
    __syncthreads();
  }

  int cr = (lane >> 4) << 2, cc = lane & 15;
#pragma unroll
  for (int i = 0; i < 4; ++i)
#pragma unroll
    for (int j = 0; j < 4; ++j) {
      size_t cb = (baseA + wr + i * 16 + cr) * (size_t)N + (baseB + wc + j * 16 + cc);
#pragma unroll
      for (int r = 0; r < 4; ++r) {
        float v = acc[i][j][r];
        if constexpr (sizeof(CT) == 2) C[cb + (size_t)r * N] = (CT)f2bf(v);
        else                           C[cb + (size_t)r * N] = v;
      }
    }
}

// ---------------- row LayerNorm (fp32 in) -> bf16 out + INVERSE row L2 norm ----------------
__global__ void ln_rows(const float* __restrict__ X, const float* __restrict__ w,
                        const float* __restrict__ b, u16* __restrict__ Y,
                        float* __restrict__ norms, int C) {
  __shared__ float red[4];
  int row = blockIdx.x;
  const float* x = X + (size_t)row * C;
  int nv = C >> 2;
  float s = 0.f, ss = 0.f;
  for (int i = threadIdx.x; i < nv; i += 256) {
    float4 v = ((const float4*)x)[i];
    s += v.x + v.y + v.z + v.w;
    ss += v.x * v.x + v.y * v.y + v.z * v.z + v.w * v.w;
  }
  s = blk_sum(s, red);
  ss = blk_sum(ss, red);
  float mean = s / C;
  float inv = rsqrtf(fmaxf(ss / C - mean * mean, 0.f) + 1e-5f);
  float nrm = 0.f;
  for (int i = threadIdx.x; i < nv; i += 256) {
    float4 v = ((const float4*)x)[i];
    float4 wv = ((const float4*)w)[i];
    float4 bv = ((const float4*)b)[i];
    float y0 = (v.x - mean) * inv * wv.x + bv.x;
    float y1 = (v.y - mean) * inv * wv.y + bv.y;
    float y2 = (v.z - mean) * inv * wv.z + bv.z;
    float y3 = (v.w - mean) * inv * wv.w + bv.w;
    nrm += y0 * y0 + y1 * y1 + y2 * y2 + y3 * y3;
    us4 o; o.x = f2bf(y0); o.y = f2bf(y1); o.z = f2bf(y2); o.w = f2bf(y3);
    ((us4*)(Y + (size_t)row * C))[i] = o;
  }
  nrm = blk_sum(nrm, red);
  if (threadIdx.x == 0) norms[row] = invnorm(nrm);
}

// ------- eff proto (generic, C wide, optional T1): E = proto + LN(T0[+T1]) -------
__global__ void ln_add_norm(const u16* __restrict__ T0, const u16* __restrict__ T1,
                            const float* __restrict__ P,
                            const float* __restrict__ w, const float* __restrict__ b,
                            u16* __restrict__ E, float* __restrict__ norms, int C) {
  __shared__ float red[4];
  int row = blockIdx.x;
  const us4* t0 = (const us4*)(T0 + (size_t)row * C);
  const us4* t1 = T1 ? (const us4*)(T1 + (size_t)row * C) : nullptr;
  const float* p = P + (size_t)row * C;
  int nv = C >> 2;
  float s = 0.f, ss = 0.f;
  for (int i = threadIdx.x; i < nv; i += 256) {
    us4 v = t0[i];
    float f0 = bf2f(v.x), f1 = bf2f(v.y), f2 = bf2f(v.z), f3 = bf2f(v.w);
    if (t1) {
      us4 v1 = t1[i];
      f0 += bf2f(v1.x); f1 += bf2f(v1.y); f2 += bf2f(v1.z); f3 += bf2f(v1.w);
    }
    s += f0 + f1 + f2 + f3;
    ss += f0 * f0 + f1 * f1 + f2 * f2 + f3 * f3;
  }
  s = blk_sum(s, red);
  ss = blk_sum(ss, red);
  float mean = s / C;
  float inv = rsqrtf(fmaxf(ss / C - mean * mean, 0.f) + 1e-5f);
  float nrm = 0.f;
  for (int i = threadIdx.x; i < nv; i += 256) {
    us4 v = t0[i];
    float f0 = bf2f(v.x), f1 = bf2f(v.y), f2 = bf2f(v.z), f3 = bf2f(v.w);
    if (t1) {
      us4 v1 = t1[i];
      f0 += bf2f(v1.x); f1 += bf2f(v1.y); f2 += bf2f(v1.z); f3 += bf2f(v1.w);
    }
    float4 pv = ((const float4*)p)[i];
    float4 wv = ((const float4*)w)[i];
    float4 bv = ((const float4*)b)[i];
    float y0 = pv.x + (f0 - mean) * inv * wv.x + bv.x;
    float y1 = pv.y + (f1 - mean) * inv * wv.y + bv.y;
    float y2 = pv.z + (f2 - mean) * inv * wv.z + bv.z;
    float y3 = pv.w + (f3 - mean) * inv * wv.w + bv.w;
    nrm += y0 * y0 + y1 * y1 + y2 * y2 + y3 * y3;
    us4 o; o.x = f2bf(y0); o.y = f2bf(y1); o.z = f2bf(y2); o.w = f2bf(y3);
    *(us4*)(E + (size_t)row * C + (i << 2)) = o;
  }
  nrm = blk_sum(nrm, red);
  if (threadIdx.x == 0) norms[row] = invnorm(nrm);
}

// ------- merged eff-proto LN for the three C=1024 protos (z = blockIdx.y) -------
struct Lan3 {
  const u16* T[3];
  const float* P[3]; const float* w[3]; const float* b[3];
  u16* E[3]; float* nr[3]; int M[3];
};
__global__ void lan_many(Lan3 L) {
  __shared__ float red[4];
  int z = blockIdx.y;
  int row = blockIdx.x;
  if (row >= L.M[z]) return;                 // block-uniform: safe w.r.t. syncs
  int i = threadIdx.x;                        // C=1024 -> one us4 per thread
  us4 v = ((const us4*)(L.T[z] + (size_t)row * 1024))[i];
  float f0 = bf2f(v.x), f1 = bf2f(v.y), f2 = bf2f(v.z), f3 = bf2f(v.w);
  float s = blk_sum(f0 + f1 + f2 + f3, red);
  float ss = blk_sum(f0 * f0 + f1 * f1 + f2 * f2 + f3 * f3, red);
  float mean = s * (1.f / 1024.f);
  float inv = rsqrtf(fmaxf(ss * (1.f / 1024.f) - mean * mean, 0.f) + 1e-5f);
  float4 pv = ((const float4*)(L.P[z] + (size_t)row * 1024))[i];
  float4 wv = ((const float4*)L.w[z])[i];
  float4 bv = ((const float4*)L.b[z])[i];
  float y0 = pv.x + (f0 - mean) * inv * wv.x + bv.x;
  float y1 = pv.y + (f1 - mean) * inv * wv.y + bv.y;
  float y2 = pv.z + (f2 - mean) * inv * wv.z + bv.z;
  float y3 = pv.w + (f3 - mean) * inv * wv.w + bv.w;
  us4 o; o.x = f2bf(y0); o.y = f2bf(y1); o.z = f2bf(y2); o.w = f2bf(y3);
  ((us4*)(L.E[z] + (size_t)row * 1024))[i] = o;
  float nrm = blk_sum(y0 * y0 + y1 * y1 + y2 * y2 + y3 * y3, red);
  if (threadIdx.x == 0) L.nr[z][row] = invnorm(nrm);
}

// ---------------- INVERSE row L2 norm of a bf16 matrix ----------------
__global__ void rownorm_bf(const u16* __restrict__ X, float* __restrict__ norms, int C) {
  __shared__ float red[4];
  int row = blockIdx.x;
  const us4* x = (const us4*)(X + (size_t)row * C);
  int nv = C >> 2;
  float nrm = 0.f;
  for (int i = threadIdx.x; i < nv; i += 256) {
    us4 v = x[i];
    float a = bf2f(v.x), b = bf2f(v.y), c = bf2f(v.z), d = bf2f(v.w);
    nrm += a * a + b * b + c * c + d * d;
  }
  nrm = blk_sum(nrm, red);
  if (threadIdx.x == 0) norms[row] = invnorm(nrm);
}

// ---- SPL epilogue core (stacked-block G rows of width 2C); rr/cn are INVERSE norms ----
__device__ __forceinline__ void epi4(const u16* gr, int C, int c, float rr,
                                     const float* bias, const float* gate,
                                     const float* cn, float* o) {
  us4 cv = *(const us4*)(gr + c);
  us4 dv = *(const us4*)(gr + C + c);
  float4 bv = *(const float4*)(bias + c);
  float4 gv = *(const float4*)(gate + c);
  float4 nv = *(const float4*)(cn + c);
  float cf[4] = {bf2f(cv.x), bf2f(cv.y), bf2f(cv.z), bf2f(cv.w)};
  float df[4] = {bf2f(dv.x), bf2f(dv.y), bf2f(dv.z), bf2f(dv.w)};
  float bb[4] = {bv.x, bv.y, bv.z, bv.w};
  float gg[4] = {gv.x, gv.y, gv.z, gv.w};
  float nn[4] = {nv.x, nv.y, nv.z, nv.w};
#pragma unroll
  for (int j = 0; j < 4; ++j) {
    float sc = df[j] * (rr * nn[j]);
    o[j] = (cf[j] + bb[j]) * fmaxf(sc - gg[j], 0.f);
  }
}

// --------- fused qkv SPL epilogue + RoPE, one block per row ----------
__global__ void spl_rope_row(const u16* __restrict__ G, const float* __restrict__ bias,
                             const float* __restrict__ gate, const float* __restrict__ rn,
                             const float* __restrict__ cn, const float* __restrict__ CT_,
                             const float* __restrict__ ST_, u16* __restrict__ MQ) {
  int r = blockIdx.x;
  int s = r & 2047;
  const u16* gr = G + (size_t)r * 6144;
  u16* outr = MQ + (size_t)r * 3072;
  float rr = rn[r];
  int t = threadIdx.x;

  int qk = (t >> 7);              // 0 = q, 1 = k
  int c = qk * 1024 + ((t & 127) << 2);
  int d = c - qk * 1024;
  float a0[4], a1[4];
  epi4(gr, 3072, c, rr, bias, gate, cn, a0);
  epi4(gr, 3072, c + 512, rr, bias, gate, cn, a1);
  const float* ct = CT_ + (size_t)s * 1024;
  const float* st = ST_ + (size_t)s * 1024;
  float4 c0 = *(const float4*)(ct + d);
  float4 s0 = *(const float4*)(st + d);
  float4 c1 = *(const float4*)(ct + d + 512);
  float4 s1 = *(const float4*)(st + d + 512);
  float cc0[4] = {c0.x, c0.y, c0.z, c0.w}, ss0[4] = {s0.x, s0.y, s0.z, s0.w};
  float cc1[4] = {c1.x, c1.y, c1.z, c1.w}, ss1[4] = {s1.x, s1.y, s1.z, s1.w};
  us4 o0, o1;
  o0.x = f2bf(a0[0] * cc0[0] - a1[0] * ss0[0]);
  o0.y = f2bf(a0[1] * cc0[1] - a1[1] * ss0[1]);
  o0.z = f2bf(a0[2] * cc0[2] - a1[2] * ss0[2]);
  o0.w = f2bf(a0[3] * cc0[3] - a1[3] * ss0[3]);
  o1.x = f2bf(a1[0] * cc1[0] + a0[0] * ss1[0]);
  o1.y = f2bf(a1[1] * cc1[1] + a0[1] * ss1[1]);
  o1.z = f2bf(a1[2] * cc1[2] + a0[2] * ss1[2]);
  o1.w = f2bf(a1[3] * cc1[3] + a0[3] * ss1[3]);
  *(us4*)(outr + c) = o0;
  *(us4*)(outr + c + 512) = o1;

  int cv_ = 2048 + (t << 2);
  float vv[4];
  epi4(gr, 3072, cv_, rr, bias, gate, cn, vv);
  us4 ov; ov.x = f2bf(vv[0]); ov.y = f2bf(vv[1]); ov.z = f2bf(vv[2]); ov.w = f2bf(vv[3]);
  *(us4*)(outr + cv_) = ov;
}

// --------- fused f1 SPL epilogue (relu) + INVERSE row norm of h ---------
__global__ void spl_f1_row(const u16* __restrict__ G, const float* __restrict__ bias,
                           const float* __restrict__ gate, const float* __restrict__ rn,
                           const float* __restrict__ cn, u16* __restrict__ H,
                           float* __restrict__ rn_h) {
  __shared__ float red[4];
  int r = blockIdx.x;
  const u16* gr = G + (size_t)r * 8192;
  u16* hr = H + (size_t)r * 4096;
  float rr = rn[r];
  float nrm = 0.f;
  for (int c = threadIdx.x << 2; c < 4096; c += 1024) {
    float o[4];
    epi4(gr, 4096, c, rr, bias, gate, cn, o);
#pragma unroll
    for (int j = 0; j < 4; ++j) {
      o[j] = fmaxf(o[j], 0.f);
      nrm += o[j] * o[j];
    }
    us4 ov; ov.x = f2bf(o[0]); ov.y = f2bf(o[1]); ov.z = f2bf(o[2]); ov.w = f2bf(o[3]);
    *(us4*)(hr + c) = ov;
  }
  nrm = blk_sum(nrm, red);
  if (threadIdx.x == 0) rn_h[r] = invnorm(nrm);
}

// --- fused o SPL + residual -> X1 (fp32), then LN2 -> bf16 + inverse rn_ffn ---
__global__ void spl_o_ln_row(const u16* __restrict__ G, const float* __restrict__ bias,
                             const float* __restrict__ gate, const float* __restrict__ rn,
                             const float* __restrict__ cn, const float* __restrict__ xres,
                             const float* __restrict__ lw, const float* __restrict__ lb,
                             float* __restrict__ X1, u16* __restrict__ Y,
                             float* __restrict__ rn_ffn) {
  __shared__ float red[4];
  int r = blockIdx.x;
  int c = threadIdx.x << 2;
  const u16* gr = G + (size_t)r * 2048;
  float o[4];
  epi4(gr, 1024, c, rn[r], bias, gate, cn, o);
  float4 rv = *(const float4*)(xres + (size_t)r * 1024 + c);
  o[0] += rv.x; o[1] += rv.y; o[2] += rv.z; o[3] += rv.w;
  float4 xo = {o[0], o[1], o[2], o[3]};
  *(float4*)(X1 + (size_t)r * 1024 + c) = xo;
  float s = o[0] + o[1] + o[2] + o[3];
  float ss = o[0] * o[0] + o[1] * o[1] + o[2] * o[2] + o[3] * o[3];
  s = blk_sum(s, red);
  ss = blk_sum(ss, red);
  float mean = s * (1.f / 1024.f);
  float inv = rsqrtf(fmaxf(ss * (1.f / 1024.f) - mean * mean, 0.f) + 1e-5f);
  float4 wv = *(const float4*)(lw + c);
  float4 bv = *(const float4*)(lb + c);
  float ww[4] = {wv.x, wv.y, wv.z, wv.w}, bb[4] = {bv.x, bv.y, bv.z, bv.w};
  float nrm = 0.f;
  us4 ov;
  u16* op = (u16*)&ov;
#pragma unroll
  for (int j = 0; j < 4; ++j) {
    float y = (o[j] - mean) * inv * ww[j] + bb[j];
    nrm += y * y;
    op[j] = f2bf(y);
  }
  *(us4*)(Y + (size_t)r * 1024 + c) = ov;
  nrm = blk_sum(nrm, red);
  if (threadIdx.x == 0) rn_ffn[r] = invnorm(nrm);
}

// ------ final SPL epilogue: bf16 split-K partial pair + residual -> fp32 out ------
__global__ void spl_epi_p(const u16* __restrict__ G0, const u16* __restrict__ G1,
                          const float* __restrict__ bias, const float* __restrict__ gate,
                          const float* __restrict__ rn, const float* __restrict__ cn,
                          const float* __restrict__ resid, float* __restrict__ out) {
  int r = blockIdx.x;
  int c = threadIdx.x << 2;
  size_t rowb = (size_t)r * 2048;
  us4 c0 = *(const us4*)(G0 + rowb + c);
  us4 c1 = *(const us4*)(G1 + rowb + c);
  us4 d0 = *(const us4*)(G0 + rowb + 1024 + c);
  us4 d1 = *(const us4*)(G1 + rowb + 1024 + c);
  float4 bv = *(const float4*)(bias + c);
  float4 gv = *(const float4*)(gate + c);
  float4 nv = *(const float4*)(cn + c);
  float4 rv = *(const float4*)(resid + (size_t)r * 1024 + c);
  float rr = rn[r];
  float cf[4] = {bf2f(c0.x) + bf2f(c1.x), bf2f(c0.y) + bf2f(c1.y),
                 bf2f(c0.z) + bf2f(c1.z), bf2f(c0.w) + bf2f(c1.w)};
  float df[4] = {bf2f(d0.x) + bf2f(d1.x), bf2f(d0.y) + bf2f(d1.y),
                 bf2f(d0.z) + bf2f(d1.z), bf2f(d0.w) + bf2f(d1.w)};
  float bb[4] = {bv.x, bv.y, bv.z, bv.w};
  float gg[4] = {gv.x, gv.y, gv.z, gv.w};
  float nn[4] = {nv.x, nv.y, nv.z, nv.w};
  float re[4] = {rv.x, rv.y, rv.z, rv.w};
  float4 ov;
  float* op = (float*)&ov;
#pragma unroll
  for (int j = 0; j < 4; ++j) {
    float sc = df[j] * (rr * nn[j]);
    op[j] = (cf[j] + bb[j]) * fmaxf(sc - gg[j], 0.f) + re[j];
  }
  *(float4*)(out + (size_t)r * 1024 + c) = ov;
}

// ---------------- V transpose (bf16 m_qkv -> VT[b][d][s]) ----------------
__global__ void vtrans(const u16* __restrict__ MQ, u16* __restrict__ VT) {
  __shared__ u16 tile[32][33];
  int b = blockIdx.z;
  int s0 = blockIdx.x << 5, d0 = blockIdx.y << 5;
  int tx = threadIdx.x, ty = threadIdx.y;
  for (int r = ty; r < 32; r += 8)
    tile[r][tx] = MQ[((size_t)(b * 2048 + s0 + r)) * 3072 + 2048 + d0 + tx];
  __syncthreads();
  for (int r = ty; r < 32; r += 8)
    VT[(size_t)b * 1024 * 2048 + (size_t)(d0 + r) * 2048 + s0 + tx] = tile[tx][r];
}

// ---- causal softmax over [2][2048][2048] bf16 scores, scale 1/32 -> bf16 P ----
__global__ void softmax_causal(const u16* __restrict__ S, u16* __restrict__ P) {
  __shared__ float red[4];
  int b = blockIdx.x >> 11;
  int q = blockIdx.x & 2047;
  const u16* row = S + ((size_t)b << 22) + (size_t)q * 2048;
  u16* prow = P + ((size_t)b << 22) + (size_t)q * 2048;
  int nv = q + 1;
  int wcap = ((q >> 7) + 1) << 7;
  int base = threadIdx.x * 8;
  float e[8];
  float m = -3.4e38f;
  float xv[8];
  bool live = base < nv;
  if (live) {
    us4 a = *(const us4*)(row + base);
    us4 bq = *(const us4*)(row + base + 4);
    xv[0] = bf2f(a.x); xv[1] = bf2f(a.y); xv[2] = bf2f(a.z); xv[3] = bf2f(a.w);
    xv[4] = bf2f(bq.x); xv[5] = bf2f(bq.y); xv[6] = bf2f(bq.z); xv[7] = bf2f(bq.w);
#pragma unroll
    for (int j = 0; j < 8; ++j) {
      xv[j] *= 0.03125f;
      if (base + j < nv) m = fmaxf(m, xv[j]);
    }
  }
  m = blk_max(m, red);
  float ssum = 0.f;
#pragma unroll
  for (int j = 0; j < 8; ++j) {
    e[j] = (live && base + j < nv) ? __expf(xv[j] - m) : 0.f;
    ssum += e[j];
  }
  ssum = blk_sum(ssum, red);
  float invs = 1.f / ssum;
  if (base < wcap) {
    us4 o;
    o.x = f2bf(e[0] * invs); o.y = f2bf(e[1] * invs);
    o.z = f2bf(e[2] * invs); o.w = f2bf(e[3] * invs);
    ((us4*)prow)[threadIdx.x * 2] = o;
    o.x = f2bf(e[4] * invs); o.y = f2bf(e[5] * invs);
    o.z = f2bf(e[6] * invs); o.w = f2bf(e[7] * invs);
    ((us4*)prow)[threadIdx.x * 2 + 1] = o;
  }
}

// =============================== launcher ===============================
extern "C" void kernel_launch(void* const* d_in, const int* in_sizes, int n_in,
                              void* d_out, int out_size, void* d_ws, size_t ws_size,
                              hipStream_t stream) {
  (void)in_sizes;
  const float* x         = (const float*)d_in[0];
  const float* cosT      = (const float*)d_in[1];
  const float* sinT      = (const float*)d_in[2];
  const float* ln1_w     = (const float*)d_in[3];
  const float* ln1_b     = (const float*)d_in[4];
  const float* ln2_w     = (const float*)d_in[5];
  const float* ln2_b     = (const float*)d_in[6];
  const float* qkv_mu    = (const float*)d_in[7];
  const float* qkv_proto = (const float*)d_in[8];
  const float* qkv_bias  = (const float*)d_in[9];
  const float* qkv_gate  = (const float*)d_in[10];
  const float* o_mu      = (const float*)d_in[11];
  const float* o_proto   = (const float*)d_in[12];
  const float* o_bias    = (const float*)d_in[13];
  const float* o_gate    = (const float*)d_in[14];
  const float* f1_mu     = (const float*)d_in[15];
  const float* f1_proto  = (const float*)d_in[16];
  const float* f1_bias   = (const float*)d_in[17];
  const float* f1_gate   = (const float*)d_in[18];
  const float* f2_mu     = (const float*)d_in[19];
  const float* f2_proto  = (const float*)d_in[20];
  const float* f2_bias   = (const float*)d_in[21];
  const float* f2_gate   = (const float*)d_in[22];
  const float* pt_qkv    = (const float*)d_in[23];
  const float* pt_o      = (const float*)d_in[24];
  const float* pt_f1     = (const float*)d_in[25];
  const float* pt_f2     = (const float*)d_in[26];
  const float* pln_qkv_w = (const float*)d_in[27];
  const float* pln_qkv_b = (const float*)d_in[28];
  const float* pln_o_w   = (const float*)d_in[29];
  const float* pln_o_b   = (const float*)d_in[30];
  const float* pln_f1_w  = (const float*)d_in[31];
  const float* pln_f1_b  = (const float*)d_in[32];
  const float* pln_f2_w  = (const float*)d_in[33];
  const float* pln_f2_b  = (const float*)d_in[34];
  const float* prev_qkv  = (const float*)d_in[35];
  const float* prev_o    = (const float*)d_in[36];
  const float* prev_f1   = (const float*)d_in[37];
  const float* prev_f2   = (const float*)d_in[38];

  const long D = 1024, TD = 3072, FD = 4096, R = 4096;

  char* W = (char*)d_ws;
  size_t off = 0;
  auto alloc = [&](size_t bytes) {
    void* p = W + off;
    off = (off + bytes + 255) & ~(size_t)255;
    return p;
  };
  char* GOUT = (char*)alloc(67108864);   // staging / G / scores+P / f2 partials
  u16*  RC   = (u16*)alloc(33554432);    // proto T / m_qkv / h
  u16*  wq   = (u16*)alloc(2 * TD * D * 2);   // [mu; eff] stacked along N
  u16*  wo   = (u16*)alloc(2 * D * D * 2);
  u16*  wf1  = (u16*)alloc(2 * FD * D * 2);
  u16*  wf2  = (u16*)alloc(2 * D * FD * 2);
  float* X1  = (float*)alloc(R * D * 4);
  u16*  P1   = (u16*)alloc(R * D * 2);        // attn_in / ffn_in bf16
  u16*  VT   = (u16*)alloc(2 * D * 2048 * 2);
  u16*  AOB  = (u16*)alloc(R * D * 2);
  float* pnq     = (float*)alloc(TD * 4);
  float* pno     = (float*)alloc(D * 4);
  float* pnf1    = (float*)alloc(FD * 4);
  float* pnf2    = (float*)alloc(D * 4);
  float* rn_ain  = (float*)alloc(R * 4);
  float* rn_aout = (float*)alloc(R * 4);
  float* rn_ffn  = (float*)alloc(R * 4);
  float* rn_h    = (float*)alloc(R * 4);
  size_t need = off;

  if (n_in < 39 || need > ws_size) {
    long n = out_size;
    fillv<<<dim3((unsigned)((n + 255) / 256)), 256, 0, stream>>>((float*)d_out, n, 12345.0f);
    return;
  }

  // overlays inside GOUT (staging packed 0..64MB, all dead before phase 2)
  u16* SA  = (u16*)GOUT;                      // prev f1/qkv/o @ 0, 8MB, 16MB
  u16* SB  = (u16*)(GOUT + 18874368);         // pt f1/qkv/o @ 18MB + 2MB stride
  u16* PF2 = (u16*)(GOUT + 25165824);         // prev_f2 @ 24MB (8MB)
  u16* TF2 = (u16*)(GOUT + 33554432);         // pt_f2   @ 32MB (32MB)
  u16* SCORESB = (u16*)GOUT;                  // [2][2048][2048] bf16 = 16 MiB
  u16* PB = (u16*)(GOUT + 16777216);          // [2][2048][2048] bf16 = 16 MiB

  // ---- phase 1: ALL weight conversions in ONE exact-grid launch ----
  {
    CvtN12 c;
    c.s[0]  = prev_f1;  c.d[0]  = SA;            c.n4[0]  = (FD * D) >> 2;
    c.s[1]  = prev_qkv; c.d[1]  = SA + 4194304;  c.n4[1]  = (TD * D) >> 2;
    c.s[2]  = prev_o;   c.d[2]  = SA + 8388608;  c.n4[2]  = (D * D) >> 2;
    c.s[3]  = pt_f1;    c.d[3]  = SB;            c.n4[3]  = (D * D) >> 2;
    c.s[4]  = pt_qkv;   c.d[4]  = SB + 1048576;  c.n4[4]  = (D * D) >> 2;
    c.s[5]  = pt_o;     c.d[5]  = SB + 2097152;  c.n4[5]  = (D * D) >> 2;
    c.s[6]  = qkv_mu;   c.d[6]  = wq;            c.n4[6]  = (TD * D) >> 2;
    c.s[7]  = f1_mu;    c.d[7]  = wf1;           c.n4[7]  = (FD * D) >> 2;
    c.s[8]  = o_mu;     c.d[8]  = wo;            c.n4[8]  = (D * D) >> 2;
    c.s[9]  = f2_mu;    c.d[9]  = wf2;           c.n4[9]  = (D * FD) >> 2;
    c.s[10] = prev_f2;  c.d[10] = PF2;           c.n4[10] = (D * FD) >> 2;
    c.s[11] = pt_f2;    c.d[11] = TF2;           c.n4[11] = ((long)FD * FD) >> 2;
    int ofs = 0;
    for (int k = 0; k < 12; ++k) {
      c.bofs[k] = ofs;
      ofs += (int)((c.n4[k] + 255) >> 8);
    }
    c.bofs[12] = ofs;                            // 44032 blocks total, zero waste
    cvt_many<<<dim3((unsigned)ofs), 256, 0, stream>>>(c);
  }
  // batched qkv/o/f1 proto GEMMs: z=0 f1(M=4096), z=1 qkv(3072), z=2 o(1024)
  {
    long Mz = 4096L | (3072L << 16) | (1024L << 32);
    gemm_bt<u16><<<dim3(32, 8, 3), 256, 0, stream>>>(
        SA, SB, RC, 4096, 1024, 1024, 1024, 1024, 5, 4194304, Mz, 4194304);
  }
  // merged eff-proto LN (three C=1024 protos)
  {
    Lan3 L;
    L.T[0] = RC;           L.P[0] = f1_proto;  L.w[0] = pln_f1_w;  L.b[0] = pln_f1_b;
    L.E[0] = wf1 + (size_t)FD * D;  L.nr[0] = pnf1;  L.M[0] = 4096;
    L.T[1] = RC + 4194304; L.P[1] = qkv_proto; L.w[1] = pln_qkv_w; L.b[1] = pln_qkv_b;
    L.E[1] = wq + (size_t)TD * D;   L.nr[1] = pnq;   L.M[1] = 3072;
    L.T[2] = RC + 8388608; L.P[2] = o_proto;   L.w[2] = pln_o_w;   L.b[2] = pln_o_b;
    L.E[2] = wo + (size_t)D * D;    L.nr[2] = pno;   L.M[2] = 1024;
    lan_many<<<dim3(4096, 3), 256, 0, stream>>>(L);
  }
  // f2 proto: split-K x2 GEMM (after lan_many has consumed RC), LN-add
  gemm_bt<u16><<<dim3(8, 32, 2), 256, 0, stream>>>(
      PF2, TF2, RC, 1024, 4096, 4096, 4096, 4096, 1, 0, 0, 0);
  ln_add_norm<<<1024, 256, 0, stream>>>(RC, RC + 4194304, f2_proto, pln_f2_w, pln_f2_b,
                                        wf2 + (size_t)D * FD, pnf2, 4096);

  // ---- phase 2: attention input LN + qkv GEMM (gemm256, 4-slot ring) + RoPE epi ----
  ln_rows<<<4096, 256, 0, stream>>>(x, ln1_w, ln1_b, P1, rn_ain, 1024);
  gemm256<u16><<<dim3(16, 24), 512, 131072, stream>>>(
      P1, wq, (u16*)GOUT, 4096, 6144, 1024, 1024, 1024, 0);
  spl_rope_row<<<4096, 256, 0, stream>>>(
      (u16*)GOUT, qkv_bias, qkv_gate, rn_ain, pnq, cosT, sinT, RC);

  // ---- phase 3: attention (batched, bf16 scores) ----
  vtrans<<<dim3(64, 32, 2), dim3(32, 8), 0, stream>>>(RC, VT);
  gemm_bt<u16><<<dim3(136, 1, 2), 256, 0, stream>>>(
      RC, RC + 1024, SCORESB, 2048, 2048, 1024, 3072, 3072,
      3, 2048L * 3072, 2048L * 3072, 1L << 22);
  softmax_causal<<<4096, 256, 0, stream>>>(SCORESB, PB);
  gemm_bt<u16><<<dim3(16, 8, 2), 256, 0, stream>>>(
      PB, VT, AOB, 2048, 1024, 2048, 2048, 2048,
      4, 1L << 22, 1024L * 2048, 2048L * 1024);
  rownorm_bf<<<4096, 256, 0, stream>>>(AOB, rn_aout, 1024);

  // ---- phase 4: fused o SPL + residual + LN2 ----
  gemm_bt<u16><<<dim3(32, 16, 1), 256, 0, stream>>>(
      AOB, wo, (u16*)GOUT, 4096, 2048, 1024, 1024, 1024, 0, 0, 0, 0);
  spl_o_ln_row<<<4096, 256, 0, stream>>>(
      (u16*)GOUT, o_bias, o_gate, rn_aout, pno, x, ln2_w, ln2_b, X1, P1, rn_ffn);

  // ---- phase 5: FFN ----
  gemm256<u16><<<dim3(16, 32), 512, 131072, stream>>>(
      P1, wf1, (u16*)GOUT, 4096, 8192, 1024, 1024, 1024, 0);
  spl_f1_row<<<4096, 256, 0, stream>>>(
      (u16*)GOUT, f1_bias, f1_gate, rn_ffn, pnf1, RC, rn_h);      // h -> RC
  gemm256<u16><<<dim3(16, 8, 2), 512, 131072, stream>>>(
      RC, wf2, (u16*)GOUT, 4096, 2048, 4096, 4096, 4096, 2048);
  spl_epi_p<<<4096, 256, 0, stream>>>(
      (u16*)GOUT, (u16*)GOUT + 8388608, f2_bias, f2_gate, rn_h, pnf2,
      X1, (float*)d_out);
}

// Round 15
// 553.760 us; speedup vs baseline: 1.0153x; 1.0039x over previous
//
#include <hip/hip_runtime.h>
#include <cstdint>

typedef unsigned short u16;
typedef __attribute__((ext_vector_type(8))) short sh8;   // 8 bf16 (4 VGPRs)
typedef __attribute__((ext_vector_type(4))) float f32x4;

struct __align__(8) us4 { u16 x, y, z, w; };

__device__ __forceinline__ u16 f2bf(float f) {
  unsigned u = __float_as_uint(f);
  u += 0x7FFFu + ((u >> 16) & 1u);   // RNE
  return (u16)(u >> 16);
}
__device__ __forceinline__ float bf2f(u16 h) {
  return __uint_as_float((unsigned)h << 16);
}
// inverse norm: 1/max(sqrt(x),1e-12) == min(rsqrt(x),1e12)
__device__ __forceinline__ float invnorm(float nrm) {
  return fminf(rsqrtf(nrm), 1e12f);
}

// ---------------- block reductions (blockDim.x == 256) ----------------
__device__ __forceinline__ float blk_sum(float v, float* red) {
#pragma unroll
  for (int o = 32; o; o >>= 1) v += __shfl_xor(v, o);
  __syncthreads();
  if ((threadIdx.x & 63) == 0) red[threadIdx.x >> 6] = v;
  __syncthreads();
  return red[0] + red[1] + red[2] + red[3];
}
__device__ __forceinline__ float blk_max(float v, float* red) {
#pragma unroll
  for (int o = 32; o; o >>= 1) v = fmaxf(v, __shfl_xor(v, o));
  __syncthreads();
  if ((threadIdx.x & 63) == 0) red[threadIdx.x >> 6] = v;
  __syncthreads();
  return fmaxf(fmaxf(red[0], red[1]), fmaxf(red[2], red[3]));
}

__global__ void fillv(float* __restrict__ o, long n, float v) {
  long i = (long)blockIdx.x * blockDim.x + threadIdx.x;
  if (i < n) o[i] = v;
}

// ------- merged fp32 -> bf16, EXACT 1-D grid via block-offset prefix table -------
struct CvtN12 {
  const float* s[12];
  u16* d[12];
  long n4[12];
  int bofs[13];   // block-offset prefix; grid.x == bofs[12]
};
__global__ void cvt_many(CvtN12 c) {
  int blk = blockIdx.x;
  int z = 0;
  while (z < 11 && blk >= c.bofs[z + 1]) ++z;   // block-uniform scalar scan
  long i = (long)(blk - c.bofs[z]) * blockDim.x + threadIdx.x;
  if (i >= c.n4[z]) return;
  float4 v = ((const float4*)c.s[z])[i];
  us4 o; o.x = f2bf(v.x); o.y = f2bf(v.y); o.z = f2bf(v.z); o.w = f2bf(v.w);
  ((us4*)c.d[z])[i] = o;
}

#define GL16(gp, lp)                                                        \
  __builtin_amdgcn_global_load_lds(                                         \
      (const __attribute__((address_space(1))) void*)(gp),                  \
      (__attribute__((address_space(3))) void*)(lp), 16, 0, 0)

// ---- gemm256 body (256x256 tile, 8 waves, 4-slot 128KiB ring, counted vmcnt,
//      XOR bank-swizzle, T5 setprio) — round-10/12 verified configuration ----
#define G256_PROLOG()                                                          \
  extern __shared__ u16 lds[];   /* 4 slots x (A 8192 + B 8192) u16 = 128KiB */\
  int tid = threadIdx.x;                                                       \
  int wid = tid >> 6, lane = tid & 63;                                         \
  int wm = wid >> 2, wn = wid & 3;                                             \
  int bm = blockIdx.x, bn = blockIdx.y;                                        \
  int k0s = 0, nt;                                                             \
  if (kchunk) {                                                                \
    k0s = blockIdx.z * kchunk;                                                 \
    nt = kchunk >> 5;                                                          \
  } else {                                                                     \
    nt = K >> 5;                                                               \
  }                                                                            \
  const size_t baseArow = (size_t)bm * 256;                                    \
  const size_t baseBrow = (size_t)bn * 256;                                    \
  int ci = (wid << 6) + lane;                                                  \
  int rowS = ci >> 2;                                                          \
  int kcS = (ci ^ (ci >> 3)) & 3;                                              \
  const u16* gA0 = A + (baseArow + rowS) * lda + k0s + kcS * 8;                \
  const u16* gA1 = gA0 + (size_t)128 * lda;                                    \
  const u16* gB0 = B + (baseBrow + rowS) * ldb + k0s + kcS * 8;                \
  const u16* gB1 = gB0 + (size_t)128 * ldb;                                    \
  u16* dBase = lds + (wid << 9);                                               \
  int l15 = lane & 15, l4 = lane >> 4;                                         \
  int aoff[8], boff[4];                                                        \
  _Pragma("unroll") for (int fr = 0; fr < 8; ++fr) {                           \
    int by = (wm * 128 + fr * 16 + l15) * 64 + l4 * 16;                        \
    aoff[fr] = (by ^ (((by >> 7) & 3) << 4)) >> 1;                             \
  }                                                                            \
  _Pragma("unroll") for (int fc = 0; fc < 4; ++fc) {                           \
    int by = (wn * 64 + fc * 16 + l15) * 64 + l4 * 16;                         \
    boff[fc] = 8192 + ((by ^ (((by >> 7) & 3) << 4)) >> 1);                    \
  }                                                                            \
  f32x4 acc[8][4];                                                             \
  const f32x4 zf = {0.f, 0.f, 0.f, 0.f};                                       \
  _Pragma("unroll") for (int i = 0; i < 8; ++i)                                \
    _Pragma("unroll") for (int j = 0; j < 4; ++j) acc[i][j] = zf;

#define STAGE256(ts)                                                  \
  do {                                                                \
    int ss_ = (ts) & 3;                                               \
    int kk_ = (ts) << 5;                                              \
    u16* d_ = dBase + ss_ * 16384;                                    \
    GL16(gA0 + kk_, d_);                                              \
    GL16(gA1 + kk_, d_ + 4096);                                       \
    GL16(gB0 + kk_, d_ + 8192);                                       \
    GL16(gB1 + kk_, d_ + 12288);                                      \
  } while (0)

#define G256_KLOOP()                                                           \
  STAGE256(0);                                                                 \
  STAGE256(1);                                                                 \
  STAGE256(2);                                                                 \
  asm volatile("s_waitcnt vmcnt(8)" ::: "memory");                             \
  __builtin_amdgcn_s_barrier();                                                \
  __builtin_amdgcn_sched_barrier(0);                                           \
  for (int t = 0; t < nt; ++t) {                                               \
    int ts = t + 3;                                                            \
    if (ts < nt) STAGE256(ts);                                                 \
    const u16* sl = lds + (t & 3) * 16384;                                     \
    sh8 af[8], bfv[4];                                                         \
    _Pragma("unroll") for (int fc = 0; fc < 4; ++fc)                           \
        bfv[fc] = *(const sh8*)(sl + boff[fc]);                                \
    _Pragma("unroll") for (int fr = 0; fr < 8; ++fr)                           \
        af[fr] = *(const sh8*)(sl + aoff[fr]);                                 \
    __builtin_amdgcn_s_setprio(1);                                             \
    _Pragma("unroll") for (int fr = 0; fr < 8; ++fr)                           \
      _Pragma("unroll") for (int fc = 0; fc < 4; ++fc)                         \
        acc[fr][fc] = __builtin_amdgcn_mfma_f32_16x16x32_bf16(                 \
            af[fr], bfv[fc], acc[fr][fc], 0, 0, 0);                            \
    __builtin_amdgcn_s_setprio(0);                                             \
    int rem = nt - 2 - t;                                                      \
    if (rem >= 2)      asm volatile("s_waitcnt vmcnt(8)" ::: "memory");        \
    else if (rem == 1) asm volatile("s_waitcnt vmcnt(4)" ::: "memory");        \
    else if (rem == 0) asm volatile("s_waitcnt vmcnt(0)" ::: "memory");        \
    if (t < nt - 1) {                                                          \
      __builtin_amdgcn_s_barrier();                                            \
      __builtin_amdgcn_sched_barrier(0);                                       \
    }                                                                          \
  }

// ================= plain 256x256 pipelined GEMM: C = A @ B^T =================
// kchunk > 0: split-K over blockIdx.z (C += z*M*N).
template <typename CT>
__global__ __launch_bounds__(512, 1) void gemm256(
    const u16* __restrict__ A, const u16* __restrict__ B, CT* __restrict__ C,
    int M, int N, int K, int lda, int ldb, int kchunk) {
  if (kchunk) C += (size_t)blockIdx.z * M * (size_t)N;
  G256_PROLOG();
  G256_KLOOP();
  // C/D layout (m89): col = lane&15, row = (lane>>4)*4 + reg
  int cr = l4 << 2, cc = l15;
  const size_t rbase = baseArow + wm * 128 + cr;
  const size_t cbase = baseBrow + wn * 64 + cc;
#pragma unroll
  for (int fr = 0; fr < 8; ++fr)
#pragma unroll
    for (int fc = 0; fc < 4; ++fc) {
      size_t cb = (rbase + fr * 16) * (size_t)N + cbase + fc * 16;
#pragma unroll
      for (int r = 0; r < 4; ++r) {
        float v = acc[fr][fc][r];
        if constexpr (sizeof(CT) == 2) C[cb + (size_t)r * N] = (CT)f2bf(v);
        else                           C[cb + (size_t)r * N] = v;
      }
    }
}

// ---------------- bf16 GEMM: C[M,N] = A[M,K] @ B[N,K]^T (128^2, m97) ----------------
// mode 0: plain | 1: split-K z | 2: batched z | 3: batched + causal tri |
// mode 4: batched + causal K-cap | 5: multi-M batched (Mz packed in zsB)
template <typename CT>
__global__ __launch_bounds__(256, 2) void gemm_bt(
    const u16* __restrict__ A, const u16* __restrict__ B, CT* __restrict__ C,
    int M, int N, int K, int lda, int ldb,
    int mode, long zsA, long zsB, long zsC) {
  int bm, bn;
  int z = blockIdx.z;
  if (mode == 3) {
    int t = blockIdx.x;
    int m = (int)floorf((sqrtf(8.f * t + 1.f) - 1.f) * 0.5f);
    while ((m + 1) * (m + 2) / 2 <= t) ++m;
    while (m * (m + 1) / 2 > t) --m;
    bm = m; bn = t - m * (m + 1) / 2;
  } else {
    bm = blockIdx.x; bn = blockIdx.y;
  }
  int k0s = 0, k0e = K;
  if (mode == 1) {
    int kc = K / gridDim.z;
    k0s = z * kc; k0e = k0s + kc;
    C += (size_t)z * M * (size_t)N;
  } else if (mode == 2 || mode == 3) {
    A += (size_t)z * zsA; B += (size_t)z * zsB; C += (size_t)z * zsC;
  } else if (mode == 4) {
    A += (size_t)z * zsA; B += (size_t)z * zsB; C += (size_t)z * zsC;
    k0e = (bm + 1) * 128;
  } else if (mode == 5) {
    int Mz = (int)((zsB >> (z * 16)) & 0xFFFF);
    if (bm * 128 >= Mz) return;
    A += (size_t)z * zsA; B += (size_t)z * 1048576; C += (size_t)z * zsC;
  }

  __shared__ __align__(16) u16 As[128 * 32];
  __shared__ __align__(16) u16 Bs[128 * 32];
  int tid = threadIdx.x, wid = tid >> 6, lane = tid & 63;
  int wr = (wid >> 1) << 6, wc = (wid & 1) << 6;
  int lr = lane & 15, lk = (lane >> 4) << 3;

  f32x4 acc[4][4];
  const f32x4 zf = {0.f, 0.f, 0.f, 0.f};
#pragma unroll
  for (int i = 0; i < 4; ++i)
#pragma unroll
    for (int j = 0; j < 4; ++j) acc[i][j] = zf;

  int r0 = tid >> 2, c0 = (tid & 3) << 3;
  const size_t baseA = (size_t)bm * 128, baseB = (size_t)bn * 128;
  const u16* Ab = A + baseA * lda;
  const u16* Bp = B + baseB * ldb;

  for (int k0 = k0s; k0 < k0e; k0 += 32) {
    GL16(Ab + (size_t)r0 * lda + k0 + c0, As + (wid << 9));
    GL16(Ab + (size_t)(64 + r0) * lda + k0 + c0, As + 2048 + (wid << 9));
    GL16(Bp + (size_t)r0 * ldb + k0 + c0, Bs + (wid << 9));
    GL16(Bp + (size_t)(64 + r0) * ldb + k0 + c0, Bs + 2048 + (wid << 9));
    __syncthreads();
    sh8 af[4], bfr[4];
#pragma unroll
    for (int f = 0; f < 4; ++f) {
      af[f]  = *(const sh8*)(As + (wr + f * 16 + lr) * 32 + lk);
      bfr[f] = *(const sh8*)(Bs + (wc + f * 16 + lr) * 32 + lk);
    }
#pragma unroll
    for (int i = 0; i < 4; ++i)
#pragma unroll
      for (int j = 0; j < 4; ++j)
        acc[i][j] = __builtin_amdgcn_mfma_f32_16x16x32_bf16(af[i], bfr[j], acc[i][j], 0, 0, 0);
    __syncthreads();
  }

  int cr = (lane >> 4) << 2, cc = lane & 15;
#pragma unroll
  for (int i = 0; i < 4; ++i)
#pragma unroll
    for (int j = 0; j < 4; ++j) {
      size_t cb = (baseA + wr + i * 16 + cr) * (size_t)N + (baseB + wc + j * 16 + cc);
#pragma unroll
      for (int r = 0; r < 4; ++r) {
        float v = acc[i][j][r];
        if constexpr (sizeof(CT) == 2) C[cb + (size_t)r * N] = (CT)f2bf(v);
        else                           C[cb + (size_t)r * N] = v;
      }
    }
}

// ---------------- row LayerNorm (fp32 in) -> bf16 out + INVERSE row L2 norm ----------------
__global__ void ln_rows(const float* __restrict__ X, const float* __restrict__ w,
                        const float* __restrict__ b, u16* __restrict__ Y,
                        float* __restrict__ norms, int C) {
  __shared__ float red[4];
  int row = blockIdx.x;
  const float* x = X + (size_t)row * C;
  int nv = C >> 2;
  float s = 0.f, ss = 0.f;
  for (int i = threadIdx.x; i < nv; i += 256) {
    float4 v = ((const float4*)x)[i];
    s += v.x + v.y + v.z + v.w;
    ss += v.x * v.x + v.y * v.y + v.z * v.z + v.w * v.w;
  }
  s = blk_sum(s, red);
  ss = blk_sum(ss, red);
  float mean = s / C;
  float inv = rsqrtf(fmaxf(ss / C - mean * mean, 0.f) + 1e-5f);
  float nrm = 0.f;
  for (int i = threadIdx.x; i < nv; i += 256) {
    float4 v = ((const float4*)x)[i];
    float4 wv = ((const float4*)w)[i];
    float4 bv = ((const float4*)b)[i];
    float y0 = (v.x - mean) * inv * wv.x + bv.x;
    float y1 = (v.y - mean) * inv * wv.y + bv.y;
    float y2 = (v.z - mean) * inv * wv.z + bv.z;
    float y3 = (v.w - mean) * inv * wv.w + bv.w;
    nrm += y0 * y0 + y1 * y1 + y2 * y2 + y3 * y3;
    us4 o; o.x = f2bf(y0); o.y = f2bf(y1); o.z = f2bf(y2); o.w = f2bf(y3);
    ((us4*)(Y + (size_t)row * C))[i] = o;
  }
  nrm = blk_sum(nrm, red);
  if (threadIdx.x == 0) norms[row] = invnorm(nrm);
}

// ------- eff proto (generic, C wide, optional T1): E = proto + LN(T0[+T1]) -------
__global__ void ln_add_norm(const u16* __restrict__ T0, const u16* __restrict__ T1,
                            const float* __restrict__ P,
                            const float* __restrict__ w, const float* __restrict__ b,
                            u16* __restrict__ E, float* __restrict__ norms, int C) {
  __shared__ float red[4];
  int row = blockIdx.x;
  const us4* t0 = (const us4*)(T0 + (size_t)row * C);
  const us4* t1 = T1 ? (const us4*)(T1 + (size_t)row * C) : nullptr;
  const float* p = P + (size_t)row * C;
  int nv = C >> 2;
  float s = 0.f, ss = 0.f;
  for (int i = threadIdx.x; i < nv; i += 256) {
    us4 v = t0[i];
    float f0 = bf2f(v.x), f1 = bf2f(v.y), f2 = bf2f(v.z), f3 = bf2f(v.w);
    if (t1) {
      us4 v1 = t1[i];
      f0 += bf2f(v1.x); f1 += bf2f(v1.y); f2 += bf2f(v1.z); f3 += bf2f(v1.w);
    }
    s += f0 + f1 + f2 + f3;
    ss += f0 * f0 + f1 * f1 + f2 * f2 + f3 * f3;
  }
  s = blk_sum(s, red);
  ss = blk_sum(ss, red);
  float mean = s / C;
  float inv = rsqrtf(fmaxf(ss / C - mean * mean, 0.f) + 1e-5f);
  float nrm = 0.f;
  for (int i = threadIdx.x; i < nv; i += 256) {
    us4 v = t0[i];
    float f0 = bf2f(v.x), f1 = bf2f(v.y), f2 = bf2f(v.z), f3 = bf2f(v.w);
    if (t1) {
      us4 v1 = t1[i];
      f0 += bf2f(v1.x); f1 += bf2f(v1.y); f2 += bf2f(v1.z); f3 += bf2f(v1.w);
    }
    float4 pv = ((const float4*)p)[i];
    float4 wv = ((const float4*)w)[i];
    float4 bv = ((const float4*)b)[i];
    float y0 = pv.x + (f0 - mean) * inv * wv.x + bv.x;
    float y1 = pv.y + (f1 - mean) * inv * wv.y + bv.y;
    float y2 = pv.z + (f2 - mean) * inv * wv.z + bv.z;
    float y3 = pv.w + (f3 - mean) * inv * wv.w + bv.w;
    nrm += y0 * y0 + y1 * y1 + y2 * y2 + y3 * y3;
    us4 o; o.x = f2bf(y0); o.y = f2bf(y1); o.z = f2bf(y2); o.w = f2bf(y3);
    *(us4*)(E + (size_t)row * C + (i << 2)) = o;
  }
  nrm = blk_sum(nrm, red);
  if (threadIdx.x == 0) norms[row] = invnorm(nrm);
}

// ------- merged eff-proto LN for the three C=1024 protos (z = blockIdx.y) -------
struct Lan3 {
  const u16* T[3];
  const float* P[3]; const float* w[3]; const float* b[3];
  u16* E[3]; float* nr[3]; int M[3];
};
__global__ void lan_many(Lan3 L) {
  __shared__ float red[4];
  int z = blockIdx.y;
  int row = blockIdx.x;
  if (row >= L.M[z]) return;                 // block-uniform: safe w.r.t. syncs
  int i = threadIdx.x;                        // C=1024 -> one us4 per thread
  us4 v = ((const us4*)(L.T[z] + (size_t)row * 1024))[i];
  float f0 = bf2f(v.x), f1 = bf2f(v.y), f2 = bf2f(v.z), f3 = bf2f(v.w);
  float s = blk_sum(f0 + f1 + f2 + f3, red);
  float ss = blk_sum(f0 * f0 + f1 * f1 + f2 * f2 + f3 * f3, red);
  float mean = s * (1.f / 1024.f);
  float inv = rsqrtf(fmaxf(ss * (1.f / 1024.f) - mean * mean, 0.f) + 1e-5f);
  float4 pv = ((const float4*)(L.P[z] + (size_t)row * 1024))[i];
  float4 wv = ((const float4*)L.w[z])[i];
  float4 bv = ((const float4*)L.b[z])[i];
  float y0 = pv.x + (f0 - mean) * inv * wv.x + bv.x;
  float y1 = pv.y + (f1 - mean) * inv * wv.y + bv.y;
  float y2 = pv.z + (f2 - mean) * inv * wv.z + bv.z;
  float y3 = pv.w + (f3 - mean) * inv * wv.w + bv.w;
  us4 o; o.x = f2bf(y0); o.y = f2bf(y1); o.z = f2bf(y2); o.w = f2bf(y3);
  ((us4*)(L.E[z] + (size_t)row * 1024))[i] = o;
  float nrm = blk_sum(y0 * y0 + y1 * y1 + y2 * y2 + y3 * y3, red);
  if (threadIdx.x == 0) L.nr[z][row] = invnorm(nrm);
}

// ---------------- INVERSE row L2 norm of a bf16 matrix ----------------
__global__ void rownorm_bf(const u16* __restrict__ X, float* __restrict__ norms, int C) {
  __shared__ float red[4];
  int row = blockIdx.x;
  const us4* x = (const us4*)(X + (size_t)row * C);
  int nv = C >> 2;
  float nrm = 0.f;
  for (int i = threadIdx.x; i < nv; i += 256) {
    us4 v = x[i];
    float a = bf2f(v.x), b = bf2f(v.y), c = bf2f(v.z), d = bf2f(v.w);
    nrm += a * a + b * b + c * c + d * d;
  }
  nrm = blk_sum(nrm, red);
  if (threadIdx.x == 0) norms[row] = invnorm(nrm);
}

// ---- SPL epilogue core (stacked-block G rows of width 2C); rr/cn are INVERSE norms ----
__device__ __forceinline__ void epi4(const u16* gr, int C, int c, float rr,
                                     const float* bias, const float* gate,
                                     const float* cn, float* o) {
  us4 cv = *(const us4*)(gr + c);
  us4 dv = *(const us4*)(gr + C + c);
  float4 bv = *(const float4*)(bias + c);
  float4 gv = *(const float4*)(gate + c);
  float4 nv = *(const float4*)(cn + c);
  float cf[4] = {bf2f(cv.x), bf2f(cv.y), bf2f(cv.z), bf2f(cv.w)};
  float df[4] = {bf2f(dv.x), bf2f(dv.y), bf2f(dv.z), bf2f(dv.w)};
  float bb[4] = {bv.x, bv.y, bv.z, bv.w};
  float gg[4] = {gv.x, gv.y, gv.z, gv.w};
  float nn[4] = {nv.x, nv.y, nv.z, nv.w};
#pragma unroll
  for (int j = 0; j < 4; ++j) {
    float sc = df[j] * (rr * nn[j]);
    o[j] = (cf[j] + bb[j]) * fmaxf(sc - gg[j], 0.f);
  }
}

// --------- fused qkv SPL epilogue + RoPE, one block per row ----------
__global__ void spl_rope_row(const u16* __restrict__ G, const float* __restrict__ bias,
                             const float* __restrict__ gate, const float* __restrict__ rn,
                             const float* __restrict__ cn, const float* __restrict__ CT_,
                             const float* __restrict__ ST_, u16* __restrict__ MQ) {
  int r = blockIdx.x;
  int s = r & 2047;
  const u16* gr = G + (size_t)r * 6144;
  u16* outr = MQ + (size_t)r * 3072;
  float rr = rn[r];
  int t = threadIdx.x;

  int qk = (t >> 7);              // 0 = q, 1 = k
  int c = qk * 1024 + ((t & 127) << 2);
  int d = c - qk * 1024;
  float a0[4], a1[4];
  epi4(gr, 3072, c, rr, bias, gate, cn, a0);
  epi4(gr, 3072, c + 512, rr, bias, gate, cn, a1);
  const float* ct = CT_ + (size_t)s * 1024;
  const float* st = ST_ + (size_t)s * 1024;
  float4 c0 = *(const float4*)(ct + d);
  float4 s0 = *(const float4*)(st + d);
  float4 c1 = *(const float4*)(ct + d + 512);
  float4 s1 = *(const float4*)(st + d + 512);
  float cc0[4] = {c0.x, c0.y, c0.z, c0.w}, ss0[4] = {s0.x, s0.y, s0.z, s0.w};
  float cc1[4] = {c1.x, c1.y, c1.z, c1.w}, ss1[4] = {s1.x, s1.y, s1.z, s1.w};
  us4 o0, o1;
  o0.x = f2bf(a0[0] * cc0[0] - a1[0] * ss0[0]);
  o0.y = f2bf(a0[1] * cc0[1] - a1[1] * ss0[1]);
  o0.z = f2bf(a0[2] * cc0[2] - a1[2] * ss0[2]);
  o0.w = f2bf(a0[3] * cc0[3] - a1[3] * ss0[3]);
  o1.x = f2bf(a1[0] * cc1[0] + a0[0] * ss1[0]);
  o1.y = f2bf(a1[1] * cc1[1] + a0[1] * ss1[1]);
  o1.z = f2bf(a1[2] * cc1[2] + a0[2] * ss1[2]);
  o1.w = f2bf(a1[3] * cc1[3] + a0[3] * ss1[3]);
  *(us4*)(outr + c) = o0;
  *(us4*)(outr + c + 512) = o1;

  int cv_ = 2048 + (t << 2);
  float vv[4];
  epi4(gr, 3072, cv_, rr, bias, gate, cn, vv);
  us4 ov; ov.x = f2bf(vv[0]); ov.y = f2bf(vv[1]); ov.z = f2bf(vv[2]); ov.w = f2bf(vv[3]);
  *(us4*)(outr + cv_) = ov;
}

// --------- fused f1 SPL epilogue (relu) + INVERSE row norm of h ---------
__global__ void spl_f1_row(const u16* __restrict__ G, const float* __restrict__ bias,
                           const float* __restrict__ gate, const float* __restrict__ rn,
                           const float* __restrict__ cn, u16* __restrict__ H,
                           float* __restrict__ rn_h) {
  __shared__ float red[4];
  int r = blockIdx.x;
  const u16* gr = G + (size_t)r * 8192;
  u16* hr = H + (size_t)r * 4096;
  float rr = rn[r];
  float nrm = 0.f;
  for (int c = threadIdx.x << 2; c < 4096; c += 1024) {
    float o[4];
    epi4(gr, 4096, c, rr, bias, gate, cn, o);
#pragma unroll
    for (int j = 0; j < 4; ++j) {
      o[j] = fmaxf(o[j], 0.f);
      nrm += o[j] * o[j];
    }
    us4 ov; ov.x = f2bf(o[0]); ov.y = f2bf(o[1]); ov.z = f2bf(o[2]); ov.w = f2bf(o[3]);
    *(us4*)(hr + c) = ov;
  }
  nrm = blk_sum(nrm, red);
  if (threadIdx.x == 0) rn_h[r] = invnorm(nrm);
}

// --- fused o SPL + residual -> X1 (fp32), then LN2 -> bf16 + inverse rn_ffn ---
__global__ void spl_o_ln_row(const u16* __restrict__ G, const float* __restrict__ bias,
                             const float* __restrict__ gate, const float* __restrict__ rn,
                             const float* __restrict__ cn, const float* __restrict__ xres,
                             const float* __restrict__ lw, const float* __restrict__ lb,
                             float* __restrict__ X1, u16* __restrict__ Y,
                             float* __restrict__ rn_ffn) {
  __shared__ float red[4];
  int r = blockIdx.x;
  int c = threadIdx.x << 2;
  const u16* gr = G + (size_t)r * 2048;
  float o[4];
  epi4(gr, 1024, c, rn[r], bias, gate, cn, o);
  float4 rv = *(const float4*)(xres + (size_t)r * 1024 + c);
  o[0] += rv.x; o[1] += rv.y; o[2] += rv.z; o[3] += rv.w;
  float4 xo = {o[0], o[1], o[2], o[3]};
  *(float4*)(X1 + (size_t)r * 1024 + c) = xo;
  float s = o[0] + o[1] + o[2] + o[3];
  float ss = o[0] * o[0] + o[1] * o[1] + o[2] * o[2] + o[3] * o[3];
  s = blk_sum(s, red);
  ss = blk_sum(ss, red);
  float mean = s * (1.f / 1024.f);
  float inv = rsqrtf(fmaxf(ss * (1.f / 1024.f) - mean * mean, 0.f) + 1e-5f);
  float4 wv = *(const float4*)(lw + c);
  float4 bv = *(const float4*)(lb + c);
  float ww[4] = {wv.x, wv.y, wv.z, wv.w}, bb[4] = {bv.x, bv.y, bv.z, bv.w};
  float nrm = 0.f;
  us4 ov;
  u16* op = (u16*)&ov;
#pragma unroll
  for (int j = 0; j < 4; ++j) {
    float y = (o[j] - mean) * inv * ww[j] + bb[j];
    nrm += y * y;
    op[j] = f2bf(y);
  }
  *(us4*)(Y + (size_t)r * 1024 + c) = ov;
  nrm = blk_sum(nrm, red);
  if (threadIdx.x == 0) rn_ffn[r] = invnorm(nrm);
}

// ------ final SPL epilogue: bf16 split-K partial pair + residual -> fp32 out ------
__global__ void spl_epi_p(const u16* __restrict__ G0, const u16* __restrict__ G1,
                          const float* __restrict__ bias, const float* __restrict__ gate,
                          const float* __restrict__ rn, const float* __restrict__ cn,
                          const float* __restrict__ resid, float* __restrict__ out) {
  int r = blockIdx.x;
  int c = threadIdx.x << 2;
  size_t rowb = (size_t)r * 2048;
  us4 c0 = *(const us4*)(G0 + rowb + c);
  us4 c1 = *(const us4*)(G1 + rowb + c);
  us4 d0 = *(const us4*)(G0 + rowb + 1024 + c);
  us4 d1 = *(const us4*)(G1 + rowb + 1024 + c);
  float4 bv = *(const float4*)(bias + c);
  float4 gv = *(const float4*)(gate + c);
  float4 nv = *(const float4*)(cn + c);
  float4 rv = *(const float4*)(resid + (size_t)r * 1024 + c);
  float rr = rn[r];
  float cf[4] = {bf2f(c0.x) + bf2f(c1.x), bf2f(c0.y) + bf2f(c1.y),
                 bf2f(c0.z) + bf2f(c1.z), bf2f(c0.w) + bf2f(c1.w)};
  float df[4] = {bf2f(d0.x) + bf2f(d1.x), bf2f(d0.y) + bf2f(d1.y),
                 bf2f(d0.z) + bf2f(d1.z), bf2f(d0.w) + bf2f(d1.w)};
  float bb[4] = {bv.x, bv.y, bv.z, bv.w};
  float gg[4] = {gv.x, gv.y, gv.z, gv.w};
  float nn[4] = {nv.x, nv.y, nv.z, nv.w};
  float re[4] = {rv.x, rv.y, rv.z, rv.w};
  float4 ov;
  float* op = (float*)&ov;
#pragma unroll
  for (int j = 0; j < 4; ++j) {
    float sc = df[j] * (rr * nn[j]);
    op[j] = (cf[j] + bb[j]) * fmaxf(sc - gg[j], 0.f) + re[j];
  }
  *(float4*)(out + (size_t)r * 1024 + c) = ov;
}

// ---------------- V transpose (bf16 m_qkv -> VT[b][d][s]) ----------------
__global__ void vtrans(const u16* __restrict__ MQ, u16* __restrict__ VT) {
  __shared__ u16 tile[32][33];
  int b = blockIdx.z;
  int s0 = blockIdx.x << 5, d0 = blockIdx.y << 5;
  int tx = threadIdx.x, ty = threadIdx.y;
  for (int r = ty; r < 32; r += 8)
    tile[r][tx] = MQ[((size_t)(b * 2048 + s0 + r)) * 3072 + 2048 + d0 + tx];
  __syncthreads();
  for (int r = ty; r < 32; r += 8)
    VT[(size_t)b * 1024 * 2048 + (size_t)(d0 + r) * 2048 + s0 + tx] = tile[tx][r];
}

// ---- causal softmax over [2][2048][2048] bf16 scores, scale 1/32 -> bf16 P ----
__global__ void softmax_causal(const u16* __restrict__ S, u16* __restrict__ P) {
  __shared__ float red[4];
  int b = blockIdx.x >> 11;
  int q = blockIdx.x & 2047;
  const u16* row = S + ((size_t)b << 22) + (size_t)q * 2048;
  u16* prow = P + ((size_t)b << 22) + (size_t)q * 2048;
  int nv = q + 1;
  int wcap = ((q >> 7) + 1) << 7;
  int base = threadIdx.x * 8;
  float e[8];
  float m = -3.4e38f;
  float xv[8];
  bool live = base < nv;
  if (live) {
    us4 a = *(const us4*)(row + base);
    us4 bq = *(const us4*)(row + base + 4);
    xv[0] = bf2f(a.x); xv[1] = bf2f(a.y); xv[2] = bf2f(a.z); xv[3] = bf2f(a.w);
    xv[4] = bf2f(bq.x); xv[5] = bf2f(bq.y); xv[6] = bf2f(bq.z); xv[7] = bf2f(bq.w);
#pragma unroll
    for (int j = 0; j < 8; ++j) {
      xv[j] *= 0.03125f;
      if (base + j < nv) m = fmaxf(m, xv[j]);
    }
  }
  m = blk_max(m, red);
  float ssum = 0.f;
#pragma unroll
  for (int j = 0; j < 8; ++j) {
    e[j] = (live && base + j < nv) ? __expf(xv[j] - m) : 0.f;
    ssum += e[j];
  }
  ssum = blk_sum(ssum, red);
  float invs = 1.f / ssum;
  if (base < wcap) {
    us4 o;
    o.x = f2bf(e[0] * invs); o.y = f2bf(e[1] * invs);
    o.z = f2bf(e[2] * invs); o.w = f2bf(e[3] * invs);
    ((us4*)prow)[threadIdx.x * 2] = o;
    o.x = f2bf(e[4] * invs); o.y = f2bf(e[5] * invs);
    o.z = f2bf(e[6] * invs); o.w = f2bf(e[7] * invs);
    ((us4*)prow)[threadIdx.x * 2 + 1] = o;
  }
}

// =============================== launcher ===============================
extern "C" void kernel_launch(void* const* d_in, const int* in_sizes, int n_in,
                              void* d_out, int out_size, void* d_ws, size_t ws_size,
                              hipStream_t stream) {
  (void)in_sizes;
  const float* x         = (const float*)d_in[0];
  const float* cosT      = (const float*)d_in[1];
  const float* sinT      = (const float*)d_in[2];
  const float* ln1_w     = (const float*)d_in[3];
  const float* ln1_b     = (const float*)d_in[4];
  const float* ln2_w     = (const float*)d_in[5];
  const float* ln2_b     = (const float*)d_in[6];
  const float* qkv_mu    = (const float*)d_in[7];
  const float* qkv_proto = (const float*)d_in[8];
  const float* qkv_bias  = (const float*)d_in[9];
  const float* qkv_gate  = (const float*)d_in[10];
  const float* o_mu      = (const float*)d_in[11];
  const float* o_proto   = (const float*)d_in[12];
  const float* o_bias    = (const float*)d_in[13];
  const float* o_gate    = (const float*)d_in[14];
  const float* f1_mu     = (const float*)d_in[15];
  const float* f1_proto  = (const float*)d_in[16];
  const float* f1_bias   = (const float*)d_in[17];
  const float* f1_gate   = (const float*)d_in[18];
  const float* f2_mu     = (const float*)d_in[19];
  const float* f2_proto  = (const float*)d_in[20];
  const float* f2_bias   = (const float*)d_in[21];
  const float* f2_gate   = (const float*)d_in[22];
  const float* pt_qkv    = (const float*)d_in[23];
  const float* pt_o      = (const float*)d_in[24];
  const float* pt_f1     = (const float*)d_in[25];
  const float* pt_f2     = (const float*)d_in[26];
  const float* pln_qkv_w = (const float*)d_in[27];
  const float* pln_qkv_b = (const float*)d_in[28];
  const float* pln_o_w   = (const float*)d_in[29];
  const float* pln_o_b   = (const float*)d_in[30];
  const float* pln_f1_w  = (const float*)d_in[31];
  const float* pln_f1_b  = (const float*)d_in[32];
  const float* pln_f2_w  = (const float*)d_in[33];
  const float* pln_f2_b  = (const float*)d_in[34];
  const float* prev_qkv  = (const float*)d_in[35];
  const float* prev_o    = (const float*)d_in[36];
  const float* prev_f1   = (const float*)d_in[37];
  const float* prev_f2   = (const float*)d_in[38];

  const long D = 1024, TD = 3072, FD = 4096, R = 4096;

  char* W = (char*)d_ws;
  size_t off = 0;
  auto alloc = [&](size_t bytes) {
    void* p = W + off;
    off = (off + bytes + 255) & ~(size_t)255;
    return p;
  };
  char* GOUT = (char*)alloc(67108864);   // staging / G / scores+P / f2 partials
  u16*  RC   = (u16*)alloc(33554432);    // proto T / m_qkv / h
  u16*  wq   = (u16*)alloc(2 * TD * D * 2);   // [mu; eff] stacked along N
  u16*  wo   = (u16*)alloc(2 * D * D * 2);
  u16*  wf1  = (u16*)alloc(2 * FD * D * 2);
  u16*  wf2  = (u16*)alloc(2 * D * FD * 2);
  float* X1  = (float*)alloc(R * D * 4);
  u16*  P1   = (u16*)alloc(R * D * 2);        // attn_in / ffn_in bf16
  u16*  VT   = (u16*)alloc(2 * D * 2048 * 2);
  u16*  AOB  = (u16*)alloc(R * D * 2);
  float* pnq     = (float*)alloc(TD * 4);
  float* pno     = (float*)alloc(D * 4);
  float* pnf1    = (float*)alloc(FD * 4);
  float* pnf2    = (float*)alloc(D * 4);
  float* rn_ain  = (float*)alloc(R * 4);
  float* rn_aout = (float*)alloc(R * 4);
  float* rn_ffn  = (float*)alloc(R * 4);
  float* rn_h    = (float*)alloc(R * 4);
  size_t need = off;

  if (n_in < 39 || need > ws_size) {
    long n = out_size;
    fillv<<<dim3((unsigned)((n + 255) / 256)), 256, 0, stream>>>((float*)d_out, n, 12345.0f);
    return;
  }

  // overlays inside GOUT (staging packed 0..64MB, all dead before phase 2)
  u16* SA  = (u16*)GOUT;                      // prev f1/qkv/o @ 0, 8MB, 16MB
  u16* SB  = (u16*)(GOUT + 18874368);         // pt f1/qkv/o @ 18MB + 2MB stride
  u16* PF2 = (u16*)(GOUT + 25165824);         // prev_f2 @ 24MB (8MB)
  u16* TF2 = (u16*)(GOUT + 33554432);         // pt_f2   @ 32MB (32MB)
  u16* SCORESB = (u16*)GOUT;                  // [2][2048][2048] bf16 = 16 MiB
  u16* PB = (u16*)(GOUT + 16777216);          // [2][2048][2048] bf16 = 16 MiB

  // ---- phase 1: ALL weight conversions in ONE exact-grid launch ----
  {
    CvtN12 c;
    c.s[0]  = prev_f1;  c.d[0]  = SA;            c.n4[0]  = (FD * D) >> 2;
    c.s[1]  = prev_qkv; c.d[1]  = SA + 4194304;  c.n4[1]  = (TD * D) >> 2;
    c.s[2]  = prev_o;   c.d[2]  = SA + 8388608;  c.n4[2]  = (D * D) >> 2;
    c.s[3]  = pt_f1;    c.d[3]  = SB;            c.n4[3]  = (D * D) >> 2;
    c.s[4]  = pt_qkv;   c.d[4]  = SB + 1048576;  c.n4[4]  = (D * D) >> 2;
    c.s[5]  = pt_o;     c.d[5]  = SB + 2097152;  c.n4[5]  = (D * D) >> 2;
    c.s[6]  = qkv_mu;   c.d[6]  = wq;            c.n4[6]  = (TD * D) >> 2;
    c.s[7]  = f1_mu;    c.d[7]  = wf1;           c.n4[7]  = (FD * D) >> 2;
    c.s[8]  = o_mu;     c.d[8]  = wo;            c.n4[8]  = (D * D) >> 2;
    c.s[9]  = f2_mu;    c.d[9]  = wf2;           c.n4[9]  = (D * FD) >> 2;
    c.s[10] = prev_f2;  c.d[10] = PF2;           c.n4[10] = (D * FD) >> 2;
    c.s[11] = pt_f2;    c.d[11] = TF2;           c.n4[11] = ((long)FD * FD) >> 2;
    int ofs = 0;
    for (int k = 0; k < 12; ++k) {
      c.bofs[k] = ofs;
      ofs += (int)((c.n4[k] + 255) >> 8);
    }
    c.bofs[12] = ofs;                            // 44032 blocks total, zero waste
    cvt_many<<<dim3((unsigned)ofs), 256, 0, stream>>>(c);
  }
  // batched qkv/o/f1 proto GEMMs: z=0 f1(M=4096), z=1 qkv(3072), z=2 o(1024)
  {
    long Mz = 4096L | (3072L << 16) | (1024L << 32);
    gemm_bt<u16><<<dim3(32, 8, 3), 256, 0, stream>>>(
        SA, SB, RC, 4096, 1024, 1024, 1024, 1024, 5, 4194304, Mz, 4194304);
  }
  // merged eff-proto LN (three C=1024 protos)
  {
    Lan3 L;
    L.T[0] = RC;           L.P[0] = f1_proto;  L.w[0] = pln_f1_w;  L.b[0] = pln_f1_b;
    L.E[0] = wf1 + (size_t)FD * D;  L.nr[0] = pnf1;  L.M[0] = 4096;
    L.T[1] = RC + 4194304; L.P[1] = qkv_proto; L.w[1] = pln_qkv_w; L.b[1] = pln_qkv_b;
    L.E[1] = wq + (size_t)TD * D;   L.nr[1] = pnq;   L.M[1] = 3072;
    L.T[2] = RC + 8388608; L.P[2] = o_proto;   L.w[2] = pln_o_w;   L.b[2] = pln_o_b;
    L.E[2] = wo + (size_t)D * D;    L.nr[2] = pno;   L.M[2] = 1024;
    lan_many<<<dim3(4096, 3), 256, 0, stream>>>(L);
  }
  // f2 proto: split-K x2 GEMM (after lan_many has consumed RC), LN-add
  gemm_bt<u16><<<dim3(8, 32, 2), 256, 0, stream>>>(
      PF2, TF2, RC, 1024, 4096, 4096, 4096, 4096, 1, 0, 0, 0);
  ln_add_norm<<<1024, 256, 0, stream>>>(RC, RC + 4194304, f2_proto, pln_f2_w, pln_f2_b,
                                        wf2 + (size_t)D * FD, pnf2, 4096);

  // ---- phase 2: attention input LN + qkv GEMM (gemm256, 4-slot ring) + RoPE epi ----
  ln_rows<<<4096, 256, 0, stream>>>(x, ln1_w, ln1_b, P1, rn_ain, 1024);
  gemm256<u16><<<dim3(16, 24), 512, 131072, stream>>>(
      P1, wq, (u16*)GOUT, 4096, 6144, 1024, 1024, 1024, 0);
  spl_rope_row<<<4096, 256, 0, stream>>>(
      (u16*)GOUT, qkv_bias, qkv_gate, rn_ain, pnq, cosT, sinT, RC);

  // ---- phase 3: attention (batched, bf16 scores) ----
  vtrans<<<dim3(64, 32, 2), dim3(32, 8), 0, stream>>>(RC, VT);
  gemm_bt<u16><<<dim3(136, 1, 2), 256, 0, stream>>>(
      RC, RC + 1024, SCORESB, 2048, 2048, 1024, 3072, 3072,
      3, 2048L * 3072, 2048L * 3072, 1L << 22);
  softmax_causal<<<4096, 256, 0, stream>>>(SCORESB, PB);
  gemm_bt<u16><<<dim3(16, 8, 2), 256, 0, stream>>>(
      PB, VT, AOB, 2048, 1024, 2048, 2048, 2048,
      4, 1L << 22, 1024L * 2048, 2048L * 1024);
  rownorm_bf<<<4096, 256, 0, stream>>>(AOB, rn_aout, 1024);

  // ---- phase 4: fused o SPL + residual + LN2 ----
  gemm_bt<u16><<<dim3(32, 16, 1), 256, 0, stream>>>(
      AOB, wo, (u16*)GOUT, 4096, 2048, 1024, 1024, 1024, 0, 0, 0, 0);
  spl_o_ln_row<<<4096, 256, 0, stream>>>(
      (u16*)GOUT, o_bias, o_gate, rn_aout, pno, x, ln2_w, ln2_b, X1, P1, rn_ffn);

  // ---- phase 5: FFN ----
  gemm256<u16><<<dim3(16, 32), 512, 131072, stream>>>(
      P1, wf1, (u16*)GOUT, 4096, 8192, 1024, 1024, 1024, 0);
  spl_f1_row<<<4096, 256, 0, stream>>>(
      (u16*)GOUT, f1_bias, f1_gate, rn_ffn, pnf1, RC, rn_h);      // h -> RC
  gemm256<u16><<<dim3(16, 8, 2), 512, 131072, stream>>>(
      RC, wf2, (u16*)GOUT, 4096, 2048, 4096, 4096, 4096, 2048);
  spl_epi_p<<<4096, 256, 0, stream>>>(
      (u16*)GOUT, (u16*)GOUT + 8388608, f2_bias, f2_gate, rn_h, pnf2,
      X1, (float*)d_out);
}